// Round 5
// baseline (230.877 us; speedup 1.0000x reference)
//
#include <hip/hip_runtime.h>
#include <hip/hip_bf16.h>
#include <cstdint>

// Problem constants
#define B_  128
#define F_  512
#define T_  60
#define C_  15
#define H1_ 128
#define H2_ 64

typedef short short8_t __attribute__((ext_vector_type(8)));   // 8 bf16 (4 VGPR)
typedef float f32x4    __attribute__((ext_vector_type(4)));   // MFMA acc

static __device__ __forceinline__ unsigned short f2bf(float f) {
    union { float f; uint32_t u; } v; v.f = f;
    uint32_t r = v.u + 0x7FFF + ((v.u >> 16) & 1);   // RNE
    return (unsigned short)(r >> 16);
}

// ---------------------------------------------------------------------------
// Camera-sort: ord[rank] = b, stable sort of b by cam[b]. 1 block, 128 thr.
// ---------------------------------------------------------------------------
__global__ __launch_bounds__(128) void make_order(const int* __restrict__ cam,
                                                  int* __restrict__ ord) {
    __shared__ int cs[B_];
    const int b = threadIdx.x;
    cs[b] = cam[b];
    __syncthreads();
    const int cb = cs[b];
    int rank = 0;
    #pragma unroll 16
    for (int j = 0; j < B_; ++j) {
        int cj = cs[j];
        rank += (cj < cb || (cj == cb && j < b)) ? 1 : 0;
    }
    ord[rank] = b;
}

// ---------------------------------------------------------------------------
// Repack x (B,F,T) f32 -> xT (B,64,F) bf16, t padded 60->64 with zeros.
// grid (4 f-chunks, B)
// ---------------------------------------------------------------------------
__global__ __launch_bounds__(256) void repack_x(const float* __restrict__ x,
                                                unsigned short* __restrict__ xT) {
    __shared__ float xs[128][61];
    const int f0 = blockIdx.x * 128, b = blockIdx.y, tid = threadIdx.x;
    #pragma unroll
    for (int it = 0; it < 32; ++it) {
        int idx = tid + it * 256;          // 128*64
        int fl = idx >> 6, t = idx & 63;
        if (t < T_) xs[fl][t] = x[((size_t)b * F_ + f0 + fl) * T_ + t];
    }
    __syncthreads();
    #pragma unroll
    for (int it = 0; it < 8; ++it) {
        int idx = tid + it * 256;          // 64*32
        int t = idx >> 5, f4 = (idx & 31) * 4;
        ushort4 o;
        o.x = (t < T_) ? f2bf(xs[f4 + 0][t]) : 0;
        o.y = (t < T_) ? f2bf(xs[f4 + 1][t]) : 0;
        o.z = (t < T_) ? f2bf(xs[f4 + 2][t]) : 0;
        o.w = (t < T_) ? f2bf(xs[f4 + 3][t]) : 0;
        *(ushort4*)(xT + ((size_t)b * 64 + t) * F_ + f0 + f4) = o;
    }
}

// ---------------------------------------------------------------------------
// Repack W1 (C,F,H1,3,4) f32 -> W1b[(c*12+pq)][i][f] bf16  ([n][k], B^T form)
// ---------------------------------------------------------------------------
__global__ __launch_bounds__(256) void repack_w1(const float* __restrict__ W1,
                                                 unsigned short* __restrict__ W1b) {
    __shared__ float ls[32][384];
    const int f0 = blockIdx.x * 32, i0 = blockIdx.y * 32, c = blockIdx.z;
    const int tid = threadIdx.x;
    #pragma unroll
    for (int it = 0; it < 12; ++it) {
        int idx = tid + it * 256;              // 3072 float4
        int fl = idx / 96, r = idx - fl * 96;
        float4 v = *(const float4*)(W1 + ((size_t)(c * F_ + f0 + fl)) * (H1_ * 12)
                                       + (size_t)i0 * 12 + r * 4);
        *(float4*)&ls[fl][r * 4] = v;
    }
    __syncthreads();
    const int i_l = tid >> 3, f_l = (tid & 7) * 4;
    #pragma unroll
    for (int pq = 0; pq < 12; ++pq) {
        ushort4 o;
        o.x = f2bf(ls[f_l + 0][i_l * 12 + pq]);
        o.y = f2bf(ls[f_l + 1][i_l * 12 + pq]);
        o.z = f2bf(ls[f_l + 2][i_l * 12 + pq]);
        o.w = f2bf(ls[f_l + 3][i_l * 12 + pq]);
        *(ushort4*)(W1b + (((size_t)(c * 12 + pq)) * H1_ + i0 + i_l) * F_ + f0 + f_l) = o;
    }
}

// ---------------------------------------------------------------------------
// Repack W2 (C,H1,H2,3,4) f32 -> W2b[(c*12+rs)][o][i] bf16
// ---------------------------------------------------------------------------
__global__ __launch_bounds__(256) void repack_w2(const float* __restrict__ W2,
                                                 unsigned short* __restrict__ W2b) {
    __shared__ float ls[32][384];
    const int i0 = blockIdx.x * 32, o0 = blockIdx.y * 32, c = blockIdx.z;
    const int tid = threadIdx.x;
    #pragma unroll
    for (int it = 0; it < 12; ++it) {
        int idx = tid + it * 256;
        int il = idx / 96, r = idx - il * 96;
        float4 v = *(const float4*)(W2 + ((size_t)(c * H1_ + i0 + il)) * (H2_ * 12)
                                       + (size_t)o0 * 12 + r * 4);
        *(float4*)&ls[il][r * 4] = v;
    }
    __syncthreads();
    const int o_l = tid >> 3, i_l = (tid & 7) * 4;
    #pragma unroll
    for (int rs = 0; rs < 12; ++rs) {
        ushort4 o;
        o.x = f2bf(ls[i_l + 0][o_l * 12 + rs]);
        o.y = f2bf(ls[i_l + 1][o_l * 12 + rs]);
        o.z = f2bf(ls[i_l + 2][o_l * 12 + rs]);
        o.w = f2bf(ls[i_l + 3][o_l * 12 + rs]);
        *(ushort4*)(W2b + (((size_t)(c * 12 + rs)) * H2_ + o0 + o_l) * H1_ + i0 + i_l) = o;
    }
}

// ---------------------------------------------------------------------------
// Fused MFMA decoder, v5: all operands global->register (L2-hot after
// camera-sort), LDS only for h1 (17.4 KB), zero K-loop barriers, one barrier
// total. 1536 blocks XCD-swizzled over camera-sorted sample positions.
// Phase1: per wave, 3-slot register pipeline (loads 2 k-steps ahead; compiler
//   emits counted vmcnt for pure reg loads). 128 MFMA/wave.
// Phase2: per wave, 3 whole rs GEMMs; B prefetch 1 seg ahead; seg-0 loads
//   issued BEFORE the barrier (latency hidden under epilogue + ds_reads).
// ---------------------------------------------------------------------------
__global__ __launch_bounds__(256, 4) void fused_mfma(
    const unsigned short* __restrict__ xT, const unsigned short* __restrict__ W1b,
    const unsigned short* __restrict__ W2b, const int* __restrict__ cam,
    const int* __restrict__ ord,
    const float* __restrict__ b1, const float* __restrict__ b2,
    const float* __restrict__ W3, const float* __restrict__ b3,
    float* __restrict__ out)
{
    __shared__ __align__(16) unsigned short h1s[64 * 136];   // 17408 B

    const int idx = blockIdx.x;
    const int swz = (idx & 7) * 192 + (idx >> 3);   // bijective XCD swizzle
    const int bpos = swz / 12, pq = swz - bpos * 12;
    const int b = ord[bpos];

    const int tid = threadIdx.x;
    const int w = tid >> 6, l = tid & 63;
    const int l15 = l & 15, g = l >> 4;
    const int c = cam[b];

    // ---------------- Phase 1 ----------------
    // A row = t (l15 per 16-lane group), k contiguous; B row = i (32w+16ni+l15)
    const unsigned short* Ap = xT + (size_t)b * (64 * F_) + (size_t)l15 * F_ + 8 * g;
    const unsigned short* Bp = W1b + ((size_t)(c * 12 + pq) * H1_ + 32 * w + l15) * F_ + 8 * g;

    f32x4 acc1[4][2];
    #pragma unroll
    for (int mt = 0; mt < 4; ++mt) {
        acc1[mt][0] = (f32x4){0.f, 0.f, 0.f, 0.f};
        acc1[mt][1] = (f32x4){0.f, 0.f, 0.f, 0.f};
    }

    short8_t afs[3][4], bfs[3][2];
    #pragma unroll
    for (int pk = 0; pk < 2; ++pk) {
        #pragma unroll
        for (int mt = 0; mt < 4; ++mt)
            afs[pk][mt] = *(const short8_t*)(Ap + mt * (16 * F_) + pk * 32);
        #pragma unroll
        for (int ni = 0; ni < 2; ++ni)
            bfs[pk][ni] = *(const short8_t*)(Bp + ni * (16 * F_) + pk * 32);
    }

    #pragma unroll
    for (int ks = 0; ks < 16; ++ks) {
        const int cur = ks % 3;
        if (ks < 14) {
            const int nx = (ks + 2) % 3;
            #pragma unroll
            for (int mt = 0; mt < 4; ++mt)
                afs[nx][mt] = *(const short8_t*)(Ap + mt * (16 * F_) + (ks + 2) * 32);
            #pragma unroll
            for (int ni = 0; ni < 2; ++ni)
                bfs[nx][ni] = *(const short8_t*)(Bp + ni * (16 * F_) + (ks + 2) * 32);
        }
        #pragma unroll
        for (int mt = 0; mt < 4; ++mt)
            #pragma unroll
            for (int ni = 0; ni < 2; ++ni)
                acc1[mt][ni] = __builtin_amdgcn_mfma_f32_16x16x32_bf16(
                    afs[cur][mt], bfs[cur][ni], acc1[mt][ni], 0, 0, 0);
    }

    // phase-2 seg-0 B prefetch, issued before the barrier (T14)
    const unsigned short* W2base = W2b + (size_t)(c * 12 + w * 3) * (H2_ * H1_)
                                 + (size_t)l15 * H1_ + 8 * g;
    short8_t bfr[2][4];
    #pragma unroll
    for (int kk = 0; kk < 4; ++kk)
        bfr[0][kk] = *(const short8_t*)(W2base + kk * 32);

    // bias + relu -> h1s (C layout: row t = 16mt+4g+r, col i = 32w+16ni+l15)
    #pragma unroll
    for (int ni = 0; ni < 2; ++ni) {
        const int i = 32 * w + 16 * ni + l15;
        const float b1v = b1[c * H1_ + i];
        #pragma unroll
        for (int mt = 0; mt < 4; ++mt)
            #pragma unroll
            for (int r = 0; r < 4; ++r) {
                float h = acc1[mt][ni][r] + b1v;
                h = h > 0.f ? h : 0.f;
                h1s[(16 * mt + 4 * g + r) * 136 + i] = f2bf(h);
            }
    }
    __syncthreads();

    // ---------------- Phase 2 ----------------
    short8_t a2[4][4];
    #pragma unroll
    for (int mt = 0; mt < 4; ++mt)
        #pragma unroll
        for (int kk = 0; kk < 4; ++kk)
            a2[mt][kk] = *(const short8_t*)&h1s[(16 * mt + l15) * 136 + 32 * kk + 8 * g];

    float w3v[4], b2v[4];
    #pragma unroll
    for (int nt = 0; nt < 4; ++nt) {
        w3v[nt] = W3[c * H2_ + 16 * nt + l15];
        b2v[nt] = b2[c * H2_ + 16 * nt + l15];
    }
    const float b3v = b3[c];
    const int p = pq >> 2, q = pq & 3;

    float s[4][4];
    #pragma unroll
    for (int mt = 0; mt < 4; ++mt) { s[mt][0] = s[mt][1] = s[mt][2] = s[mt][3] = 0.f; }

    // seg = 0..11 : rs_local = seg>>2, nt = seg&3
    #pragma unroll
    for (int seg = 0; seg < 12; ++seg) {
        if (seg < 11) {
            const int ns = seg + 1;
            const unsigned short* nb = W2base + (size_t)(ns >> 2) * (H2_ * H1_)
                                     + (ns & 3) * (16 * H1_);
            #pragma unroll
            for (int kk = 0; kk < 4; ++kk)
                bfr[(seg + 1) & 1][kk] = *(const short8_t*)(nb + kk * 32);
        }
        const int nt = seg & 3;
        #pragma unroll
        for (int mt = 0; mt < 4; ++mt) {
            f32x4 acc2 = (f32x4){0.f, 0.f, 0.f, 0.f};
            #pragma unroll
            for (int kk = 0; kk < 4; ++kk)
                acc2 = __builtin_amdgcn_mfma_f32_16x16x32_bf16(
                    a2[mt][kk], bfr[seg & 1][kk], acc2, 0, 0, 0);
            #pragma unroll
            for (int r = 0; r < 4; ++r)
                s[mt][r] += w3v[nt] * fmaxf(acc2[r] + b2v[nt], 0.f);
        }

        if (nt == 3) {
            const int rs = w * 3 + (seg >> 2);
            const int hrow = p * 3 + (rs >> 2), wcol = q * 4 + (rs & 3);
            #pragma unroll
            for (int mt = 0; mt < 4; ++mt)
                #pragma unroll
                for (int r = 0; r < 4; ++r) {
                    float v = s[mt][r];
                    v += __shfl_xor(v, 1); v += __shfl_xor(v, 2);
                    v += __shfl_xor(v, 4); v += __shfl_xor(v, 8);
                    if (l15 == 0) {
                        const int t = 16 * mt + 4 * g + r;
                        if (t < T_)
                            out[(((size_t)b * T_ + t) * 9 + hrow) * 16 + wcol] =
                                1.f / (1.f + __expf(-(v + b3v)));
                    }
                    s[mt][r] = 0.f;
                }
        }
    }
}

// ---------------------------------------------------------------------------
// fp32 VALU fallback — used only if ws too small
// ---------------------------------------------------------------------------
__global__ __launch_bounds__(256) void fused_decoder_f32(
    const float* __restrict__ x,   const int* __restrict__ cam,
    const float* __restrict__ W1,  const float* __restrict__ b1,
    const float* __restrict__ W2,  const float* __restrict__ b2,
    const float* __restrict__ W3,  const float* __restrict__ b3,
    float* __restrict__ out)
{
    __shared__ float h1s[T_ * H1_];
    __shared__ float stage[8192];

    const int pq  = blockIdx.x;
    const int b   = blockIdx.y;
    const int p   = pq >> 2, q = pq & 3;
    const int tid = threadIdx.x;
    const int c   = cam[b];

    float* xs  = stage;
    float* w1s = stage + 2048;

    const int ig = tid & 31;
    const int tg = tid >> 5;

    float acc[8][4];
    #pragma unroll
    for (int a = 0; a < 8; ++a)
        #pragma unroll
        for (int j = 0; j < 4; ++j) acc[a][j] = 0.f;

    for (int f0 = 0; f0 < F_; f0 += 32) {
        __syncthreads();
        {
            int lane = tid & 63;
            int sub  = tid >> 6;
            if (lane < T_) {
                #pragma unroll
                for (int m = 0; m < 8; ++m) {
                    int kk = sub * 8 + m;
                    xs[kk * 64 + lane] = x[((size_t)b * F_ + f0 + kk) * T_ + lane];
                }
            }
        }
        for (int e = tid; e < 32 * H1_; e += 256) {
            int kk = e >> 7, i = e & 127;
            w1s[e] = W1[(((size_t)c * F_ + f0 + kk) * H1_ + i) * 12 + pq];
        }
        __syncthreads();
        #pragma unroll 8
        for (int kk = 0; kk < 32; ++kk) {
            float4 bv = *(const float4*)&w1s[kk * 128 + ig * 4];
            float4 a0 = *(const float4*)&xs[kk * 64 + tg * 8];
            float4 a1 = *(const float4*)&xs[kk * 64 + tg * 8 + 4];
            float at[8] = {a0.x, a0.y, a0.z, a0.w, a1.x, a1.y, a1.z, a1.w};
            #pragma unroll
            for (int tt = 0; tt < 8; ++tt) {
                acc[tt][0] = fmaf(at[tt], bv.x, acc[tt][0]);
                acc[tt][1] = fmaf(at[tt], bv.y, acc[tt][1]);
                acc[tt][2] = fmaf(at[tt], bv.z, acc[tt][2]);
                acc[tt][3] = fmaf(at[tt], bv.w, acc[tt][3]);
            }
        }
    }
    {
        float4 b1v = *(const float4*)&b1[c * H1_ + ig * 4];
        #pragma unroll
        for (int tt = 0; tt < 8; ++tt) {
            int t = tg * 8 + tt;
            if (t < T_) {
                float4 hv;
                hv.x = fmaxf(acc[tt][0] + b1v.x, 0.f);
                hv.y = fmaxf(acc[tt][1] + b1v.y, 0.f);
                hv.z = fmaxf(acc[tt][2] + b1v.z, 0.f);
                hv.w = fmaxf(acc[tt][3] + b1v.w, 0.f);
                *(float4*)&h1s[t * H1_ + ig * 4] = hv;
            }
        }
    }

    const int lane = tid & 63;
    const int wv   = tid >> 6;
    const float w3v = W3[c * H2_ + lane];
    const float b2v = b2[c * H2_ + lane];
    const float b3v = b3[c];
    float* w2s = stage;

    for (int rs = 0; rs < 12; ++rs) {
        __syncthreads();
        for (int e = tid; e < H1_ * H2_; e += 256) {
            int i = e >> 6, o = e & 63;
            w2s[e] = W2[(((size_t)c * H1_ + i) * H2_ + o) * 12 + rs];
        }
        __syncthreads();

        float acc2[15];
        #pragma unroll
        for (int j = 0; j < 15; ++j) acc2[j] = 0.f;

        for (int i = 0; i < H1_; i += 4) {
            float wa = w2s[(i + 0) * 64 + lane];
            float wb = w2s[(i + 1) * 64 + lane];
            float wc = w2s[(i + 2) * 64 + lane];
            float wd = w2s[(i + 3) * 64 + lane];
            #pragma unroll
            for (int j = 0; j < 15; ++j) {
                float4 h = *(const float4*)&h1s[(wv * 15 + j) * H1_ + i];
                acc2[j] = fmaf(h.x, wa, acc2[j]);
                acc2[j] = fmaf(h.y, wb, acc2[j]);
                acc2[j] = fmaf(h.z, wc, acc2[j]);
                acc2[j] = fmaf(h.w, wd, acc2[j]);
            }
        }

        const int r = rs >> 2, s = rs & 3;
        const int hrow = p * 3 + r, wcol = q * 4 + s;
        #pragma unroll
        for (int j = 0; j < 15; ++j) {
            float y = w3v * fmaxf(acc2[j] + b2v, 0.f);
            #pragma unroll
            for (int m = 32; m > 0; m >>= 1) y += __shfl_xor(y, m, 64);
            if (lane == j) {
                int t = wv * 15 + j;
                float v = y + b3v;
                out[(((size_t)b * T_ + t) * 9 + hrow) * 16 + wcol] = 1.f / (1.f + __expf(-v));
            }
        }
    }
}

// ---------------------------------------------------------------------------
extern "C" void kernel_launch(void* const* d_in, const int* in_sizes, int n_in,
                              void* d_out, int out_size, void* d_ws, size_t ws_size,
                              hipStream_t stream) {
    const float* x   = (const float*)d_in[0];
    const int*   cam = (const int*)  d_in[1];
    const float* W1  = (const float*)d_in[2];
    const float* b1  = (const float*)d_in[3];
    const float* W2  = (const float*)d_in[4];
    const float* b2  = (const float*)d_in[5];
    const float* W3  = (const float*)d_in[6];
    const float* b3  = (const float*)d_in[7];
    float* outp = (float*)d_out;

    const size_t n_xT  = (size_t)B_ * 64 * F_;          //  4,194,304
    const size_t n_w1b = (size_t)C_ * 12 * H1_ * F_;    // 11,796,480
    const size_t n_w2b = (size_t)C_ * 12 * H2_ * H1_;   //  1,474,560
    const size_t needed = (n_xT + n_w1b + n_w2b) * sizeof(unsigned short)
                        + B_ * sizeof(int);

    if (d_ws != nullptr && ws_size >= needed) {
        unsigned short* xT  = (unsigned short*)d_ws;
        unsigned short* W1p = xT + n_xT;
        unsigned short* W2p = W1p + n_w1b;
        int* ord = (int*)(W2p + n_w2b);
        make_order<<<1, 128, 0, stream>>>(cam, ord);
        repack_x <<<dim3(4, B_), 256, 0, stream>>>(x, xT);
        repack_w1<<<dim3(F_ / 32, H1_ / 32, C_), 256, 0, stream>>>(W1, W1p);
        repack_w2<<<dim3(H1_ / 32, H2_ / 32, C_), 256, 0, stream>>>(W2, W2p);
        fused_mfma<<<dim3(12 * B_), 256, 0, stream>>>(
            xT, W1p, W2p, cam, ord, b1, b2, W3, b3, outp);
    } else {
        fused_decoder_f32<<<dim3(12, B_), 256, 0, stream>>>(
            x, cam, W1, b1, W2, b2, W3, b3, outp);
    }
}

// Round 6
// 178.676 us; speedup vs baseline: 1.2922x; 1.2922x over previous
//
#include <hip/hip_runtime.h>
#include <hip/hip_bf16.h>
#include <cstdint>

// Problem constants
#define B_  128
#define F_  512
#define T_  60
#define C_  15
#define H1_ 128
#define H2_ 64

typedef short short8_t __attribute__((ext_vector_type(8)));   // 8 bf16 (4 VGPR)
typedef float f32x4    __attribute__((ext_vector_type(4)));   // MFMA acc

static __device__ __forceinline__ unsigned short f2bf(float f) {
    union { float f; uint32_t u; } v; v.f = f;
    uint32_t r = v.u + 0x7FFF + ((v.u >> 16) & 1);   // RNE
    return (unsigned short)(r >> 16);
}

// ---------------------------------------------------------------------------
// Camera-sort: ord[rank] = b, stable sort of b by cam[b]. 1 block, 128 thr.
// ---------------------------------------------------------------------------
__global__ __launch_bounds__(128) void make_order(const int* __restrict__ cam,
                                                  int* __restrict__ ord) {
    __shared__ int cs[B_];
    const int b = threadIdx.x;
    cs[b] = cam[b];
    __syncthreads();
    const int cb = cs[b];
    int rank = 0;
    #pragma unroll 16
    for (int j = 0; j < B_; ++j) {
        int cj = cs[j];
        rank += (cj < cb || (cj == cb && j < b)) ? 1 : 0;
    }
    ord[rank] = b;
}

// ---------------------------------------------------------------------------
// Repack x (B,F,T) f32 -> xT (B,64,F) bf16, t padded 60->64 with zeros.
// grid (4 f-chunks, B)
// ---------------------------------------------------------------------------
__global__ __launch_bounds__(256) void repack_x(const float* __restrict__ x,
                                                unsigned short* __restrict__ xT) {
    __shared__ float xs[128][61];
    const int f0 = blockIdx.x * 128, b = blockIdx.y, tid = threadIdx.x;
    #pragma unroll
    for (int it = 0; it < 32; ++it) {
        int idx = tid + it * 256;          // 128*64
        int fl = idx >> 6, t = idx & 63;
        if (t < T_) xs[fl][t] = x[((size_t)b * F_ + f0 + fl) * T_ + t];
    }
    __syncthreads();
    #pragma unroll
    for (int it = 0; it < 8; ++it) {
        int idx = tid + it * 256;          // 64*32
        int t = idx >> 5, f4 = (idx & 31) * 4;
        ushort4 o;
        o.x = (t < T_) ? f2bf(xs[f4 + 0][t]) : 0;
        o.y = (t < T_) ? f2bf(xs[f4 + 1][t]) : 0;
        o.z = (t < T_) ? f2bf(xs[f4 + 2][t]) : 0;
        o.w = (t < T_) ? f2bf(xs[f4 + 3][t]) : 0;
        *(ushort4*)(xT + ((size_t)b * 64 + t) * F_ + f0 + f4) = o;
    }
}

// ---------------------------------------------------------------------------
// Repack W1 (C,F,H1,3,4) f32 -> W1b[(c*12+pq)][i][f] bf16  ([n][k], B^T form)
// ---------------------------------------------------------------------------
__global__ __launch_bounds__(256) void repack_w1(const float* __restrict__ W1,
                                                 unsigned short* __restrict__ W1b) {
    __shared__ float ls[32][384];
    const int f0 = blockIdx.x * 32, i0 = blockIdx.y * 32, c = blockIdx.z;
    const int tid = threadIdx.x;
    #pragma unroll
    for (int it = 0; it < 12; ++it) {
        int idx = tid + it * 256;              // 3072 float4
        int fl = idx / 96, r = idx - fl * 96;
        float4 v = *(const float4*)(W1 + ((size_t)(c * F_ + f0 + fl)) * (H1_ * 12)
                                       + (size_t)i0 * 12 + r * 4);
        *(float4*)&ls[fl][r * 4] = v;
    }
    __syncthreads();
    const int i_l = tid >> 3, f_l = (tid & 7) * 4;
    #pragma unroll
    for (int pq = 0; pq < 12; ++pq) {
        ushort4 o;
        o.x = f2bf(ls[f_l + 0][i_l * 12 + pq]);
        o.y = f2bf(ls[f_l + 1][i_l * 12 + pq]);
        o.z = f2bf(ls[f_l + 2][i_l * 12 + pq]);
        o.w = f2bf(ls[f_l + 3][i_l * 12 + pq]);
        *(ushort4*)(W1b + (((size_t)(c * 12 + pq)) * H1_ + i0 + i_l) * F_ + f0 + f_l) = o;
    }
}

// ---------------------------------------------------------------------------
// Repack W2 (C,H1,H2,3,4) f32 -> W2b[(c*12+rs)][o][i] bf16
// ---------------------------------------------------------------------------
__global__ __launch_bounds__(256) void repack_w2(const float* __restrict__ W2,
                                                 unsigned short* __restrict__ W2b) {
    __shared__ float ls[32][384];
    const int i0 = blockIdx.x * 32, o0 = blockIdx.y * 32, c = blockIdx.z;
    const int tid = threadIdx.x;
    #pragma unroll
    for (int it = 0; it < 12; ++it) {
        int idx = tid + it * 256;
        int il = idx / 96, r = idx - il * 96;
        float4 v = *(const float4*)(W2 + ((size_t)(c * H1_ + i0 + il)) * (H2_ * 12)
                                       + (size_t)o0 * 12 + r * 4);
        *(float4*)&ls[il][r * 4] = v;
    }
    __syncthreads();
    const int o_l = tid >> 3, i_l = (tid & 7) * 4;
    #pragma unroll
    for (int rs = 0; rs < 12; ++rs) {
        ushort4 o;
        o.x = f2bf(ls[i_l + 0][o_l * 12 + rs]);
        o.y = f2bf(ls[i_l + 1][o_l * 12 + rs]);
        o.z = f2bf(ls[i_l + 2][o_l * 12 + rs]);
        o.w = f2bf(ls[i_l + 3][o_l * 12 + rs]);
        *(ushort4*)(W2b + (((size_t)(c * 12 + rs)) * H2_ + o0 + o_l) * H1_ + i0 + i_l) = o;
    }
}

// ---------------------------------------------------------------------------
// Fused MFMA decoder, v6 = v5 structure with a register budget that fits.
//   __launch_bounds__(256,3) -> ~170 VGPR cap (liveness ~140-150, no spill),
//   3 blocks/CU. All operands global->register (L2-hot after camera-sort),
//   LDS only for h1 (17.4 KB), zero K-loop barriers, one barrier total.
// Phase1: 3-slot register pipeline, loads 2 k-steps ahead.
// Phase2: 3-slot B prefetch, 2 segments ahead; seg-0/1 issued before the
//   barrier (latency hidden under epilogue + barrier + ds_reads).
// ---------------------------------------------------------------------------
__global__ __launch_bounds__(256, 3) void fused_mfma(
    const unsigned short* __restrict__ xT, const unsigned short* __restrict__ W1b,
    const unsigned short* __restrict__ W2b, const int* __restrict__ cam,
    const int* __restrict__ ord,
    const float* __restrict__ b1, const float* __restrict__ b2,
    const float* __restrict__ W3, const float* __restrict__ b3,
    float* __restrict__ out)
{
    __shared__ __align__(16) unsigned short h1s[64 * 136];   // 17408 B

    const int idx = blockIdx.x;
    const int swz = (idx & 7) * 192 + (idx >> 3);   // bijective XCD swizzle
    const int bpos = swz / 12, pq = swz - bpos * 12;
    const int b = ord[bpos];

    const int tid = threadIdx.x;
    const int w = tid >> 6, l = tid & 63;
    const int l15 = l & 15, g = l >> 4;
    const int c = cam[b];

    // ---------------- Phase 1 ----------------
    // A row = t (l15 per 16-lane group), k contiguous; B row = i (32w+16ni+l15)
    const unsigned short* Ap = xT + (size_t)b * (64 * F_) + (size_t)l15 * F_ + 8 * g;
    const unsigned short* Bp = W1b + ((size_t)(c * 12 + pq) * H1_ + 32 * w + l15) * F_ + 8 * g;

    f32x4 acc1[4][2];
    #pragma unroll
    for (int mt = 0; mt < 4; ++mt) {
        acc1[mt][0] = (f32x4){0.f, 0.f, 0.f, 0.f};
        acc1[mt][1] = (f32x4){0.f, 0.f, 0.f, 0.f};
    }

    short8_t afs[3][4], bfs[3][2];
    #pragma unroll
    for (int pk = 0; pk < 2; ++pk) {
        #pragma unroll
        for (int mt = 0; mt < 4; ++mt)
            afs[pk][mt] = *(const short8_t*)(Ap + mt * (16 * F_) + pk * 32);
        #pragma unroll
        for (int ni = 0; ni < 2; ++ni)
            bfs[pk][ni] = *(const short8_t*)(Bp + ni * (16 * F_) + pk * 32);
    }

    #pragma unroll
    for (int ks = 0; ks < 16; ++ks) {
        const int cur = ks % 3;
        if (ks < 14) {
            const int nx = (ks + 2) % 3;
            #pragma unroll
            for (int mt = 0; mt < 4; ++mt)
                afs[nx][mt] = *(const short8_t*)(Ap + mt * (16 * F_) + (ks + 2) * 32);
            #pragma unroll
            for (int ni = 0; ni < 2; ++ni)
                bfs[nx][ni] = *(const short8_t*)(Bp + ni * (16 * F_) + (ks + 2) * 32);
        }
        #pragma unroll
        for (int mt = 0; mt < 4; ++mt)
            #pragma unroll
            for (int ni = 0; ni < 2; ++ni)
                acc1[mt][ni] = __builtin_amdgcn_mfma_f32_16x16x32_bf16(
                    afs[cur][mt], bfs[cur][ni], acc1[mt][ni], 0, 0, 0);
    }

    // phase-2 seg-0/1 B prefetch, issued before the barrier (T14)
    const unsigned short* W2base = W2b + (size_t)(c * 12 + w * 3) * (H2_ * H1_)
                                 + (size_t)l15 * H1_ + 8 * g;
    short8_t bfr[3][4];
    #pragma unroll
    for (int kk = 0; kk < 4; ++kk)
        bfr[0][kk] = *(const short8_t*)(W2base + kk * 32);
    #pragma unroll
    for (int kk = 0; kk < 4; ++kk)
        bfr[1][kk] = *(const short8_t*)(W2base + 16 * H1_ + kk * 32);

    // bias + relu -> h1s (C layout: row t = 16mt+4g+r, col i = 32w+16ni+l15)
    #pragma unroll
    for (int ni = 0; ni < 2; ++ni) {
        const int i = 32 * w + 16 * ni + l15;
        const float b1v = b1[c * H1_ + i];
        #pragma unroll
        for (int mt = 0; mt < 4; ++mt)
            #pragma unroll
            for (int r = 0; r < 4; ++r) {
                float h = acc1[mt][ni][r] + b1v;
                h = h > 0.f ? h : 0.f;
                h1s[(16 * mt + 4 * g + r) * 136 + i] = f2bf(h);
            }
    }
    __syncthreads();

    // ---------------- Phase 2 ----------------
    short8_t a2[4][4];
    #pragma unroll
    for (int mt = 0; mt < 4; ++mt)
        #pragma unroll
        for (int kk = 0; kk < 4; ++kk)
            a2[mt][kk] = *(const short8_t*)&h1s[(16 * mt + l15) * 136 + 32 * kk + 8 * g];

    float w3v[4], b2v[4];
    #pragma unroll
    for (int nt = 0; nt < 4; ++nt) {
        w3v[nt] = W3[c * H2_ + 16 * nt + l15];
        b2v[nt] = b2[c * H2_ + 16 * nt + l15];
    }
    const float b3v = b3[c];
    const int p = pq >> 2, q = pq & 3;

    float s[4][4];
    #pragma unroll
    for (int mt = 0; mt < 4; ++mt) { s[mt][0] = s[mt][1] = s[mt][2] = s[mt][3] = 0.f; }

    // seg = 0..11 : rs_local = seg>>2, nt = seg&3
    #pragma unroll
    for (int seg = 0; seg < 12; ++seg) {
        if (seg < 10) {
            const int ns = seg + 2;
            const unsigned short* nb = W2base + (size_t)(ns >> 2) * (H2_ * H1_)
                                     + (ns & 3) * (16 * H1_);
            #pragma unroll
            for (int kk = 0; kk < 4; ++kk)
                bfr[(seg + 2) % 3][kk] = *(const short8_t*)(nb + kk * 32);
        }
        const int nt = seg & 3;
        #pragma unroll
        for (int mt = 0; mt < 4; ++mt) {
            f32x4 acc2 = (f32x4){0.f, 0.f, 0.f, 0.f};
            #pragma unroll
            for (int kk = 0; kk < 4; ++kk)
                acc2 = __builtin_amdgcn_mfma_f32_16x16x32_bf16(
                    a2[mt][kk], bfr[seg % 3][kk], acc2, 0, 0, 0);
            #pragma unroll
            for (int r = 0; r < 4; ++r)
                s[mt][r] += w3v[nt] * fmaxf(acc2[r] + b2v[nt], 0.f);
        }

        if (nt == 3) {
            const int rs = w * 3 + (seg >> 2);
            const int hrow = p * 3 + (rs >> 2), wcol = q * 4 + (rs & 3);
            #pragma unroll
            for (int mt = 0; mt < 4; ++mt)
                #pragma unroll
                for (int r = 0; r < 4; ++r) {
                    float v = s[mt][r];
                    v += __shfl_xor(v, 1); v += __shfl_xor(v, 2);
                    v += __shfl_xor(v, 4); v += __shfl_xor(v, 8);
                    if (l15 == 0) {
                        const int t = 16 * mt + 4 * g + r;
                        if (t < T_)
                            out[(((size_t)b * T_ + t) * 9 + hrow) * 16 + wcol] =
                                1.f / (1.f + __expf(-(v + b3v)));
                    }
                    s[mt][r] = 0.f;
                }
        }
    }
}

// ---------------------------------------------------------------------------
// fp32 VALU fallback — used only if ws too small
// ---------------------------------------------------------------------------
__global__ __launch_bounds__(256) void fused_decoder_f32(
    const float* __restrict__ x,   const int* __restrict__ cam,
    const float* __restrict__ W1,  const float* __restrict__ b1,
    const float* __restrict__ W2,  const float* __restrict__ b2,
    const float* __restrict__ W3,  const float* __restrict__ b3,
    float* __restrict__ out)
{
    __shared__ float h1s[T_ * H1_];
    __shared__ float stage[8192];

    const int pq  = blockIdx.x;
    const int b   = blockIdx.y;
    const int p   = pq >> 2, q = pq & 3;
    const int tid = threadIdx.x;
    const int c   = cam[b];

    float* xs  = stage;
    float* w1s = stage + 2048;

    const int ig = tid & 31;
    const int tg = tid >> 5;

    float acc[8][4];
    #pragma unroll
    for (int a = 0; a < 8; ++a)
        #pragma unroll
        for (int j = 0; j < 4; ++j) acc[a][j] = 0.f;

    for (int f0 = 0; f0 < F_; f0 += 32) {
        __syncthreads();
        {
            int lane = tid & 63;
            int sub  = tid >> 6;
            if (lane < T_) {
                #pragma unroll
                for (int m = 0; m < 8; ++m) {
                    int kk = sub * 8 + m;
                    xs[kk * 64 + lane] = x[((size_t)b * F_ + f0 + kk) * T_ + lane];
                }
            }
        }
        for (int e = tid; e < 32 * H1_; e += 256) {
            int kk = e >> 7, i = e & 127;
            w1s[e] = W1[(((size_t)c * F_ + f0 + kk) * H1_ + i) * 12 + pq];
        }
        __syncthreads();
        #pragma unroll 8
        for (int kk = 0; kk < 32; ++kk) {
            float4 bv = *(const float4*)&w1s[kk * 128 + ig * 4];
            float4 a0 = *(const float4*)&xs[kk * 64 + tg * 8];
            float4 a1 = *(const float4*)&xs[kk * 64 + tg * 8 + 4];
            float at[8] = {a0.x, a0.y, a0.z, a0.w, a1.x, a1.y, a1.z, a1.w};
            #pragma unroll
            for (int tt = 0; tt < 8; ++tt) {
                acc[tt][0] = fmaf(at[tt], bv.x, acc[tt][0]);
                acc[tt][1] = fmaf(at[tt], bv.y, acc[tt][1]);
                acc[tt][2] = fmaf(at[tt], bv.z, acc[tt][2]);
                acc[tt][3] = fmaf(at[tt], bv.w, acc[tt][3]);
            }
        }
    }
    {
        float4 b1v = *(const float4*)&b1[c * H1_ + ig * 4];
        #pragma unroll
        for (int tt = 0; tt < 8; ++tt) {
            int t = tg * 8 + tt;
            if (t < T_) {
                float4 hv;
                hv.x = fmaxf(acc[tt][0] + b1v.x, 0.f);
                hv.y = fmaxf(acc[tt][1] + b1v.y, 0.f);
                hv.z = fmaxf(acc[tt][2] + b1v.z, 0.f);
                hv.w = fmaxf(acc[tt][3] + b1v.w, 0.f);
                *(float4*)&h1s[t * H1_ + ig * 4] = hv;
            }
        }
    }

    const int lane = tid & 63;
    const int wv   = tid >> 6;
    const float w3v = W3[c * H2_ + lane];
    const float b2v = b2[c * H2_ + lane];
    const float b3v = b3[c];
    float* w2s = stage;

    for (int rs = 0; rs < 12; ++rs) {
        __syncthreads();
        for (int e = tid; e < H1_ * H2_; e += 256) {
            int i = e >> 6, o = e & 63;
            w2s[e] = W2[(((size_t)c * H1_ + i) * H2_ + o) * 12 + rs];
        }
        __syncthreads();

        float acc2[15];
        #pragma unroll
        for (int j = 0; j < 15; ++j) acc2[j] = 0.f;

        for (int i = 0; i < H1_; i += 4) {
            float wa = w2s[(i + 0) * 64 + lane];
            float wb = w2s[(i + 1) * 64 + lane];
            float wc = w2s[(i + 2) * 64 + lane];
            float wd = w2s[(i + 3) * 64 + lane];
            #pragma unroll
            for (int j = 0; j < 15; ++j) {
                float4 h = *(const float4*)&h1s[(wv * 15 + j) * H1_ + i];
                acc2[j] = fmaf(h.x, wa, acc2[j]);
                acc2[j] = fmaf(h.y, wb, acc2[j]);
                acc2[j] = fmaf(h.z, wc, acc2[j]);
                acc2[j] = fmaf(h.w, wd, acc2[j]);
            }
        }

        const int r = rs >> 2, s = rs & 3;
        const int hrow = p * 3 + r, wcol = q * 4 + s;
        #pragma unroll
        for (int j = 0; j < 15; ++j) {
            float y = w3v * fmaxf(acc2[j] + b2v, 0.f);
            #pragma unroll
            for (int m = 32; m > 0; m >>= 1) y += __shfl_xor(y, m, 64);
            if (lane == j) {
                int t = wv * 15 + j;
                float v = y + b3v;
                out[(((size_t)b * T_ + t) * 9 + hrow) * 16 + wcol] = 1.f / (1.f + __expf(-v));
            }
        }
    }
}

// ---------------------------------------------------------------------------
extern "C" void kernel_launch(void* const* d_in, const int* in_sizes, int n_in,
                              void* d_out, int out_size, void* d_ws, size_t ws_size,
                              hipStream_t stream) {
    const float* x   = (const float*)d_in[0];
    const int*   cam = (const int*)  d_in[1];
    const float* W1  = (const float*)d_in[2];
    const float* b1  = (const float*)d_in[3];
    const float* W2  = (const float*)d_in[4];
    const float* b2  = (const float*)d_in[5];
    const float* W3  = (const float*)d_in[6];
    const float* b3  = (const float*)d_in[7];
    float* outp = (float*)d_out;

    const size_t n_xT  = (size_t)B_ * 64 * F_;          //  4,194,304
    const size_t n_w1b = (size_t)C_ * 12 * H1_ * F_;    // 11,796,480
    const size_t n_w2b = (size_t)C_ * 12 * H2_ * H1_;   //  1,474,560
    const size_t needed = (n_xT + n_w1b + n_w2b) * sizeof(unsigned short)
                        + B_ * sizeof(int);

    if (d_ws != nullptr && ws_size >= needed) {
        unsigned short* xT  = (unsigned short*)d_ws;
        unsigned short* W1p = xT + n_xT;
        unsigned short* W2p = W1p + n_w1b;
        int* ord = (int*)(W2p + n_w2b);
        make_order<<<1, 128, 0, stream>>>(cam, ord);
        repack_x <<<dim3(4, B_), 256, 0, stream>>>(x, xT);
        repack_w1<<<dim3(F_ / 32, H1_ / 32, C_), 256, 0, stream>>>(W1, W1p);
        repack_w2<<<dim3(H1_ / 32, H2_ / 32, C_), 256, 0, stream>>>(W2, W2p);
        fused_mfma<<<dim3(12 * B_), 256, 0, stream>>>(
            xT, W1p, W2p, cam, ord, b1, b2, W3, b3, outp);
    } else {
        fused_decoder_f32<<<dim3(12, B_), 256, 0, stream>>>(
            x, cam, W1, b1, W2, b2, W3, b3, outp);
    }
}

// Round 7
// 146.095 us; speedup vs baseline: 1.5803x; 1.2230x over previous
//
#include <hip/hip_runtime.h>
#include <hip/hip_bf16.h>
#include <cstdint>

// Problem constants
#define B_  128
#define F_  512
#define T_  60
#define C_  15
#define H1_ 128
#define H2_ 64

typedef short short8_t __attribute__((ext_vector_type(8)));   // 8 bf16 (4 VGPR)
typedef float f32x4    __attribute__((ext_vector_type(4)));   // MFMA acc

static __device__ __forceinline__ unsigned short f2bf(float f) {
    union { float f; uint32_t u; } v; v.f = f;
    uint32_t r = v.u + 0x7FFF + ((v.u >> 16) & 1);   // RNE
    return (unsigned short)(r >> 16);
}

// ---------------------------------------------------------------------------
// Camera-sort: ord[rank] = b, stable sort of b by cam[b]. 1 block, 128 thr.
// ---------------------------------------------------------------------------
__global__ __launch_bounds__(128) void make_order(const int* __restrict__ cam,
                                                  int* __restrict__ ord) {
    __shared__ int cs[B_];
    const int b = threadIdx.x;
    cs[b] = cam[b];
    __syncthreads();
    const int cb = cs[b];
    int rank = 0;
    #pragma unroll 16
    for (int j = 0; j < B_; ++j) {
        int cj = cs[j];
        rank += (cj < cb || (cj == cb && j < b)) ? 1 : 0;
    }
    ord[rank] = b;
}

// ---------------------------------------------------------------------------
// Repack x (B,F,T) f32 -> xT (B,64,F) bf16, t padded 60->64 with zeros.
// grid (4 f-chunks, B)
// ---------------------------------------------------------------------------
__global__ __launch_bounds__(256) void repack_x(const float* __restrict__ x,
                                                unsigned short* __restrict__ xT) {
    __shared__ float xs[128][61];
    const int f0 = blockIdx.x * 128, b = blockIdx.y, tid = threadIdx.x;
    #pragma unroll
    for (int it = 0; it < 32; ++it) {
        int idx = tid + it * 256;          // 128*64
        int fl = idx >> 6, t = idx & 63;
        if (t < T_) xs[fl][t] = x[((size_t)b * F_ + f0 + fl) * T_ + t];
    }
    __syncthreads();
    #pragma unroll
    for (int it = 0; it < 8; ++it) {
        int idx = tid + it * 256;          // 64*32
        int t = idx >> 5, f4 = (idx & 31) * 4;
        ushort4 o;
        o.x = (t < T_) ? f2bf(xs[f4 + 0][t]) : 0;
        o.y = (t < T_) ? f2bf(xs[f4 + 1][t]) : 0;
        o.z = (t < T_) ? f2bf(xs[f4 + 2][t]) : 0;
        o.w = (t < T_) ? f2bf(xs[f4 + 3][t]) : 0;
        *(ushort4*)(xT + ((size_t)b * 64 + t) * F_ + f0 + f4) = o;
    }
}

// ---------------------------------------------------------------------------
// Repack W1 (C,F,H1,3,4) f32 -> W1b[(c*12+pq)][i][f] bf16  ([n][k], B^T form)
// ---------------------------------------------------------------------------
__global__ __launch_bounds__(256) void repack_w1(const float* __restrict__ W1,
                                                 unsigned short* __restrict__ W1b) {
    __shared__ float ls[32][384];
    const int f0 = blockIdx.x * 32, i0 = blockIdx.y * 32, c = blockIdx.z;
    const int tid = threadIdx.x;
    #pragma unroll
    for (int it = 0; it < 12; ++it) {
        int idx = tid + it * 256;              // 3072 float4
        int fl = idx / 96, r = idx - fl * 96;
        float4 v = *(const float4*)(W1 + ((size_t)(c * F_ + f0 + fl)) * (H1_ * 12)
                                       + (size_t)i0 * 12 + r * 4);
        *(float4*)&ls[fl][r * 4] = v;
    }
    __syncthreads();
    const int i_l = tid >> 3, f_l = (tid & 7) * 4;
    #pragma unroll
    for (int pq = 0; pq < 12; ++pq) {
        ushort4 o;
        o.x = f2bf(ls[f_l + 0][i_l * 12 + pq]);
        o.y = f2bf(ls[f_l + 1][i_l * 12 + pq]);
        o.z = f2bf(ls[f_l + 2][i_l * 12 + pq]);
        o.w = f2bf(ls[f_l + 3][i_l * 12 + pq]);
        *(ushort4*)(W1b + (((size_t)(c * 12 + pq)) * H1_ + i0 + i_l) * F_ + f0 + f_l) = o;
    }
}

// ---------------------------------------------------------------------------
// Repack W2 (C,H1,H2,3,4) f32 -> W2b[(c*12+rs)][o][i] bf16
// ---------------------------------------------------------------------------
__global__ __launch_bounds__(256) void repack_w2(const float* __restrict__ W2,
                                                 unsigned short* __restrict__ W2b) {
    __shared__ float ls[32][384];
    const int i0 = blockIdx.x * 32, o0 = blockIdx.y * 32, c = blockIdx.z;
    const int tid = threadIdx.x;
    #pragma unroll
    for (int it = 0; it < 12; ++it) {
        int idx = tid + it * 256;
        int il = idx / 96, r = idx - il * 96;
        float4 v = *(const float4*)(W2 + ((size_t)(c * H1_ + i0 + il)) * (H2_ * 12)
                                       + (size_t)o0 * 12 + r * 4);
        *(float4*)&ls[il][r * 4] = v;
    }
    __syncthreads();
    const int o_l = tid >> 3, i_l = (tid & 7) * 4;
    #pragma unroll
    for (int rs = 0; rs < 12; ++rs) {
        ushort4 o;
        o.x = f2bf(ls[i_l + 0][o_l * 12 + rs]);
        o.y = f2bf(ls[i_l + 1][o_l * 12 + rs]);
        o.z = f2bf(ls[i_l + 2][o_l * 12 + rs]);
        o.w = f2bf(ls[i_l + 3][o_l * 12 + rs]);
        *(ushort4*)(W2b + (((size_t)(c * 12 + rs)) * H2_ + o0 + o_l) * H1_ + i0 + i_l) = o;
    }
}

// ---------------------------------------------------------------------------
// Fused MFMA decoder, v7 = v6 structure WITHOUT the VGPR cap.
//   __launch_bounds__(256) only: min-waves arg caps VGPR at 256/N and caused
//   massive scratch spill in R3-R6 (WRITE_SIZE 115-315 MB). Compiler now
//   picks its own VGPR count (~140-170) -> no spill, ~2 blocks/CU.
// All operands global->register (L2-hot after camera-sort), LDS only for h1
// (17.4 KB), zero K-loop barriers, one barrier total.
// Phase1: 3-slot register pipeline, loads 2 k-steps ahead.
// Phase2: 2-slot B prefetch, 1 segment ahead; seg-0 issued before barrier.
// ---------------------------------------------------------------------------
__global__ __launch_bounds__(256) void fused_mfma(
    const unsigned short* __restrict__ xT, const unsigned short* __restrict__ W1b,
    const unsigned short* __restrict__ W2b, const int* __restrict__ cam,
    const int* __restrict__ ord,
    const float* __restrict__ b1, const float* __restrict__ b2,
    const float* __restrict__ W3, const float* __restrict__ b3,
    float* __restrict__ out)
{
    __shared__ __align__(16) unsigned short h1s[64 * 136];   // 17408 B

    const int idx = blockIdx.x;
    const int swz = (idx & 7) * 192 + (idx >> 3);   // bijective XCD swizzle
    const int bpos = swz / 12, pq = swz - bpos * 12;
    const int b = ord[bpos];

    const int tid = threadIdx.x;
    const int w = tid >> 6, l = tid & 63;
    const int l15 = l & 15, g = l >> 4;
    const int c = cam[b];

    // ---------------- Phase 1 ----------------
    // A row = t (l15 per 16-lane group), k contiguous; B row = i (32w+16ni+l15)
    const unsigned short* Ap = xT + (size_t)b * (64 * F_) + (size_t)l15 * F_ + 8 * g;
    const unsigned short* Bp = W1b + ((size_t)(c * 12 + pq) * H1_ + 32 * w + l15) * F_ + 8 * g;

    f32x4 acc1[4][2];
    #pragma unroll
    for (int mt = 0; mt < 4; ++mt) {
        acc1[mt][0] = (f32x4){0.f, 0.f, 0.f, 0.f};
        acc1[mt][1] = (f32x4){0.f, 0.f, 0.f, 0.f};
    }

    short8_t afs[3][4], bfs[3][2];
    #pragma unroll
    for (int pk = 0; pk < 2; ++pk) {
        #pragma unroll
        for (int mt = 0; mt < 4; ++mt)
            afs[pk][mt] = *(const short8_t*)(Ap + mt * (16 * F_) + pk * 32);
        #pragma unroll
        for (int ni = 0; ni < 2; ++ni)
            bfs[pk][ni] = *(const short8_t*)(Bp + ni * (16 * F_) + pk * 32);
    }

    #pragma unroll
    for (int ks = 0; ks < 16; ++ks) {
        const int cur = ks % 3;
        if (ks < 14) {
            const int nx = (ks + 2) % 3;
            #pragma unroll
            for (int mt = 0; mt < 4; ++mt)
                afs[nx][mt] = *(const short8_t*)(Ap + mt * (16 * F_) + (ks + 2) * 32);
            #pragma unroll
            for (int ni = 0; ni < 2; ++ni)
                bfs[nx][ni] = *(const short8_t*)(Bp + ni * (16 * F_) + (ks + 2) * 32);
        }
        #pragma unroll
        for (int mt = 0; mt < 4; ++mt)
            #pragma unroll
            for (int ni = 0; ni < 2; ++ni)
                acc1[mt][ni] = __builtin_amdgcn_mfma_f32_16x16x32_bf16(
                    afs[cur][mt], bfs[cur][ni], acc1[mt][ni], 0, 0, 0);
    }

    // phase-2 seg-0 B prefetch, issued before the barrier (T14)
    const unsigned short* W2base = W2b + (size_t)(c * 12 + w * 3) * (H2_ * H1_)
                                 + (size_t)l15 * H1_ + 8 * g;
    short8_t bfr[2][4];
    #pragma unroll
    for (int kk = 0; kk < 4; ++kk)
        bfr[0][kk] = *(const short8_t*)(W2base + kk * 32);

    // bias + relu -> h1s (C layout: row t = 16mt+4g+r, col i = 32w+16ni+l15)
    #pragma unroll
    for (int ni = 0; ni < 2; ++ni) {
        const int i = 32 * w + 16 * ni + l15;
        const float b1v = b1[c * H1_ + i];
        #pragma unroll
        for (int mt = 0; mt < 4; ++mt)
            #pragma unroll
            for (int r = 0; r < 4; ++r) {
                float h = acc1[mt][ni][r] + b1v;
                h = h > 0.f ? h : 0.f;
                h1s[(16 * mt + 4 * g + r) * 136 + i] = f2bf(h);
            }
    }
    __syncthreads();

    // ---------------- Phase 2 ----------------
    short8_t a2[4][4];
    #pragma unroll
    for (int mt = 0; mt < 4; ++mt)
        #pragma unroll
        for (int kk = 0; kk < 4; ++kk)
            a2[mt][kk] = *(const short8_t*)&h1s[(16 * mt + l15) * 136 + 32 * kk + 8 * g];

    float w3v[4], b2v[4];
    #pragma unroll
    for (int nt = 0; nt < 4; ++nt) {
        w3v[nt] = W3[c * H2_ + 16 * nt + l15];
        b2v[nt] = b2[c * H2_ + 16 * nt + l15];
    }
    const float b3v = b3[c];
    const int p = pq >> 2, q = pq & 3;

    float s[4][4];
    #pragma unroll
    for (int mt = 0; mt < 4; ++mt) { s[mt][0] = s[mt][1] = s[mt][2] = s[mt][3] = 0.f; }

    // seg = 0..11 : rs_local = seg>>2, nt = seg&3
    #pragma unroll
    for (int seg = 0; seg < 12; ++seg) {
        if (seg < 11) {
            const int ns = seg + 1;
            const unsigned short* nb = W2base + (size_t)(ns >> 2) * (H2_ * H1_)
                                     + (ns & 3) * (16 * H1_);
            #pragma unroll
            for (int kk = 0; kk < 4; ++kk)
                bfr[(seg + 1) & 1][kk] = *(const short8_t*)(nb + kk * 32);
        }
        const int nt = seg & 3;
        #pragma unroll
        for (int mt = 0; mt < 4; ++mt) {
            f32x4 acc2 = (f32x4){0.f, 0.f, 0.f, 0.f};
            #pragma unroll
            for (int kk = 0; kk < 4; ++kk)
                acc2 = __builtin_amdgcn_mfma_f32_16x16x32_bf16(
                    a2[mt][kk], bfr[seg & 1][kk], acc2, 0, 0, 0);
            #pragma unroll
            for (int r = 0; r < 4; ++r)
                s[mt][r] += w3v[nt] * fmaxf(acc2[r] + b2v[nt], 0.f);
        }

        if (nt == 3) {
            const int rs = w * 3 + (seg >> 2);
            const int hrow = p * 3 + (rs >> 2), wcol = q * 4 + (rs & 3);
            #pragma unroll
            for (int mt = 0; mt < 4; ++mt)
                #pragma unroll
                for (int r = 0; r < 4; ++r) {
                    float v = s[mt][r];
                    v += __shfl_xor(v, 1); v += __shfl_xor(v, 2);
                    v += __shfl_xor(v, 4); v += __shfl_xor(v, 8);
                    if (l15 == 0) {
                        const int t = 16 * mt + 4 * g + r;
                        if (t < T_)
                            out[(((size_t)b * T_ + t) * 9 + hrow) * 16 + wcol] =
                                1.f / (1.f + __expf(-(v + b3v)));
                    }
                    s[mt][r] = 0.f;
                }
        }
    }
}

// ---------------------------------------------------------------------------
// fp32 VALU fallback — used only if ws too small
// ---------------------------------------------------------------------------
__global__ __launch_bounds__(256) void fused_decoder_f32(
    const float* __restrict__ x,   const int* __restrict__ cam,
    const float* __restrict__ W1,  const float* __restrict__ b1,
    const float* __restrict__ W2,  const float* __restrict__ b2,
    const float* __restrict__ W3,  const float* __restrict__ b3,
    float* __restrict__ out)
{
    __shared__ float h1s[T_ * H1_];
    __shared__ float stage[8192];

    const int pq  = blockIdx.x;
    const int b   = blockIdx.y;
    const int p   = pq >> 2, q = pq & 3;
    const int tid = threadIdx.x;
    const int c   = cam[b];

    float* xs  = stage;
    float* w1s = stage + 2048;

    const int ig = tid & 31;
    const int tg = tid >> 5;

    float acc[8][4];
    #pragma unroll
    for (int a = 0; a < 8; ++a)
        #pragma unroll
        for (int j = 0; j < 4; ++j) acc[a][j] = 0.f;

    for (int f0 = 0; f0 < F_; f0 += 32) {
        __syncthreads();
        {
            int lane = tid & 63;
            int sub  = tid >> 6;
            if (lane < T_) {
                #pragma unroll
                for (int m = 0; m < 8; ++m) {
                    int kk = sub * 8 + m;
                    xs[kk * 64 + lane] = x[((size_t)b * F_ + f0 + kk) * T_ + lane];
                }
            }
        }
        for (int e = tid; e < 32 * H1_; e += 256) {
            int kk = e >> 7, i = e & 127;
            w1s[e] = W1[(((size_t)c * F_ + f0 + kk) * H1_ + i) * 12 + pq];
        }
        __syncthreads();
        #pragma unroll 8
        for (int kk = 0; kk < 32; ++kk) {
            float4 bv = *(const float4*)&w1s[kk * 128 + ig * 4];
            float4 a0 = *(const float4*)&xs[kk * 64 + tg * 8];
            float4 a1 = *(const float4*)&xs[kk * 64 + tg * 8 + 4];
            float at[8] = {a0.x, a0.y, a0.z, a0.w, a1.x, a1.y, a1.z, a1.w};
            #pragma unroll
            for (int tt = 0; tt < 8; ++tt) {
                acc[tt][0] = fmaf(at[tt], bv.x, acc[tt][0]);
                acc[tt][1] = fmaf(at[tt], bv.y, acc[tt][1]);
                acc[tt][2] = fmaf(at[tt], bv.z, acc[tt][2]);
                acc[tt][3] = fmaf(at[tt], bv.w, acc[tt][3]);
            }
        }
    }
    {
        float4 b1v = *(const float4*)&b1[c * H1_ + ig * 4];
        #pragma unroll
        for (int tt = 0; tt < 8; ++tt) {
            int t = tg * 8 + tt;
            if (t < T_) {
                float4 hv;
                hv.x = fmaxf(acc[tt][0] + b1v.x, 0.f);
                hv.y = fmaxf(acc[tt][1] + b1v.y, 0.f);
                hv.z = fmaxf(acc[tt][2] + b1v.z, 0.f);
                hv.w = fmaxf(acc[tt][3] + b1v.w, 0.f);
                *(float4*)&h1s[t * H1_ + ig * 4] = hv;
            }
        }
    }

    const int lane = tid & 63;
    const int wv   = tid >> 6;
    const float w3v = W3[c * H2_ + lane];
    const float b2v = b2[c * H2_ + lane];
    const float b3v = b3[c];
    float* w2s = stage;

    for (int rs = 0; rs < 12; ++rs) {
        __syncthreads();
        for (int e = tid; e < H1_ * H2_; e += 256) {
            int i = e >> 6, o = e & 63;
            w2s[e] = W2[(((size_t)c * H1_ + i) * H2_ + o) * 12 + rs];
        }
        __syncthreads();

        float acc2[15];
        #pragma unroll
        for (int j = 0; j < 15; ++j) acc2[j] = 0.f;

        for (int i = 0; i < H1_; i += 4) {
            float wa = w2s[(i + 0) * 64 + lane];
            float wb = w2s[(i + 1) * 64 + lane];
            float wc = w2s[(i + 2) * 64 + lane];
            float wd = w2s[(i + 3) * 64 + lane];
            #pragma unroll
            for (int j = 0; j < 15; ++j) {
                float4 h = *(const float4*)&h1s[(wv * 15 + j) * H1_ + i];
                acc2[j] = fmaf(h.x, wa, acc2[j]);
                acc2[j] = fmaf(h.y, wb, acc2[j]);
                acc2[j] = fmaf(h.z, wc, acc2[j]);
                acc2[j] = fmaf(h.w, wd, acc2[j]);
            }
        }

        const int r = rs >> 2, s = rs & 3;
        const int hrow = p * 3 + r, wcol = q * 4 + s;
        #pragma unroll
        for (int j = 0; j < 15; ++j) {
            float y = w3v * fmaxf(acc2[j] + b2v, 0.f);
            #pragma unroll
            for (int m = 32; m > 0; m >>= 1) y += __shfl_xor(y, m, 64);
            if (lane == j) {
                int t = wv * 15 + j;
                float v = y + b3v;
                out[(((size_t)b * T_ + t) * 9 + hrow) * 16 + wcol] = 1.f / (1.f + __expf(-v));
            }
        }
    }
}

// ---------------------------------------------------------------------------
extern "C" void kernel_launch(void* const* d_in, const int* in_sizes, int n_in,
                              void* d_out, int out_size, void* d_ws, size_t ws_size,
                              hipStream_t stream) {
    const float* x   = (const float*)d_in[0];
    const int*   cam = (const int*)  d_in[1];
    const float* W1  = (const float*)d_in[2];
    const float* b1  = (const float*)d_in[3];
    const float* W2  = (const float*)d_in[4];
    const float* b2  = (const float*)d_in[5];
    const float* W3  = (const float*)d_in[6];
    const float* b3  = (const float*)d_in[7];
    float* outp = (float*)d_out;

    const size_t n_xT  = (size_t)B_ * 64 * F_;          //  4,194,304
    const size_t n_w1b = (size_t)C_ * 12 * H1_ * F_;    // 11,796,480
    const size_t n_w2b = (size_t)C_ * 12 * H2_ * H1_;   //  1,474,560
    const size_t needed = (n_xT + n_w1b + n_w2b) * sizeof(unsigned short)
                        + B_ * sizeof(int);

    if (d_ws != nullptr && ws_size >= needed) {
        unsigned short* xT  = (unsigned short*)d_ws;
        unsigned short* W1p = xT + n_xT;
        unsigned short* W2p = W1p + n_w1b;
        int* ord = (int*)(W2p + n_w2b);
        make_order<<<1, 128, 0, stream>>>(cam, ord);
        repack_x <<<dim3(4, B_), 256, 0, stream>>>(x, xT);
        repack_w1<<<dim3(F_ / 32, H1_ / 32, C_), 256, 0, stream>>>(W1, W1p);
        repack_w2<<<dim3(H1_ / 32, H2_ / 32, C_), 256, 0, stream>>>(W2, W2p);
        fused_mfma<<<dim3(12 * B_), 256, 0, stream>>>(
            xT, W1p, W2p, cam, ord, b1, b2, W3, b3, outp);
    } else {
        fused_decoder_f32<<<dim3(12, B_), 256, 0, stream>>>(
            x, cam, W1, b1, W2, b2, W3, b3, outp);
    }
}

// Round 9
// 104.460 us; speedup vs baseline: 2.2102x; 1.3986x over previous
//
#include <hip/hip_runtime.h>
#include <hip/hip_bf16.h>
#include <cstdint>

// Problem constants
#define B_  128
#define F_  512
#define T_  60
#define C_  15
#define H1_ 128
#define H2_ 64

typedef short short8_t __attribute__((ext_vector_type(8)));   // 8 bf16 (4 VGPR)
typedef float f32x4    __attribute__((ext_vector_type(4)));   // MFMA acc

static __device__ __forceinline__ unsigned short f2bf(float f) {
    union { float f; uint32_t u; } v; v.f = f;
    uint32_t r = v.u + 0x7FFF + ((v.u >> 16) & 1);   // RNE
    return (unsigned short)(r >> 16);
}

// async 16B global -> LDS DMA (dest = wave-uniform base + lane*16)
static __device__ __forceinline__ void async_cp16(const unsigned short* g, unsigned short* l) {
    __builtin_amdgcn_global_load_lds(
        (const __attribute__((address_space(1))) unsigned int*)g,
        (__attribute__((address_space(3))) unsigned int*)l, 16, 0, 0);
}

// ---------------------------------------------------------------------------
// Camera-sort: ord[rank] = b, stable sort of b by cam[b]. 1 block, 128 thr.
// ---------------------------------------------------------------------------
__global__ __launch_bounds__(128) void make_order(const int* __restrict__ cam,
                                                  int* __restrict__ ord) {
    __shared__ int cs[B_];
    const int b = threadIdx.x;
    cs[b] = cam[b];
    __syncthreads();
    const int cb = cs[b];
    int rank = 0;
    #pragma unroll 16
    for (int j = 0; j < B_; ++j) {
        int cj = cs[j];
        rank += (cj < cb || (cj == cb && j < b)) ? 1 : 0;
    }
    ord[rank] = b;
}

// ---------------------------------------------------------------------------
// Repack x (B,F,T) f32 -> xTs (B, 8 kc-chunks, swizzled 64x64 LDS image) bf16.
// Image unit layout (16B units): chunk kc (stride 4096 ush), row t (0..63,
//   zero-pad t>=60), unit col cc (0..7): holds k = kc*64 + (cc ^ (t&7))*8..+8
//   (XOR swizzle baked in: LINEAR global_load_lds -> swizzled LDS tile).
// grid (4 f-chunks of 128, B)
// ---------------------------------------------------------------------------
__global__ __launch_bounds__(256) void repack_x(const float* __restrict__ x,
                                                unsigned short* __restrict__ xTs) {
    __shared__ float xs[128][61];
    const int f0 = blockIdx.x * 128, b = blockIdx.y, tid = threadIdx.x;
    #pragma unroll
    for (int it = 0; it < 32; ++it) {
        int idx = tid + it * 256;          // 128*64
        int fl = idx >> 6, t = idx & 63;
        if (t < T_) xs[fl][t] = x[((size_t)b * F_ + f0 + fl) * T_ + t];
    }
    __syncthreads();
    #pragma unroll
    for (int it = 0; it < 8; ++it) {
        int idx = tid + it * 256;          // 64*32
        int t = idx >> 5, f4 = (idx & 31) * 4;
        ushort4 o;
        o.x = (t < T_) ? f2bf(xs[f4 + 0][t]) : 0;
        o.y = (t < T_) ? f2bf(xs[f4 + 1][t]) : 0;
        o.z = (t < T_) ? f2bf(xs[f4 + 2][t]) : 0;
        o.w = (t < T_) ? f2bf(xs[f4 + 3][t]) : 0;
        const int f = f0 + f4;
        const int kc = f >> 6, within = f & 63;
        const int cc = (within >> 3) ^ (t & 7), half = (within >> 2) & 1;
        *(ushort4*)(xTs + (size_t)b * 32768 + kc * 4096 + t * 64 + cc * 8 + half * 4) = o;
    }
}

// ---------------------------------------------------------------------------
// Repack W1 (C,F,H1,3,4) f32 -> W1s[(c*12+pq)][kc][swizzled 128x64 image] bf16
//   per-(c,pq) slice = 65536 ush (128 rows x 512 k); per-kc chunk = 8192 ush.
//   unit (kc, row i, cc): holds k = kc*64 + (cc ^ (i&7))*8 .. +8
// ---------------------------------------------------------------------------
__global__ __launch_bounds__(256) void repack_w1(const float* __restrict__ W1,
                                                 unsigned short* __restrict__ W1s) {
    __shared__ float ls[32][384];
    const int f0 = blockIdx.x * 32, i0 = blockIdx.y * 32, c = blockIdx.z;
    const int tid = threadIdx.x;
    #pragma unroll
    for (int it = 0; it < 12; ++it) {
        int idx = tid + it * 256;              // 3072 float4
        int fl = idx / 96, r = idx - fl * 96;
        float4 v = *(const float4*)(W1 + ((size_t)(c * F_ + f0 + fl)) * (H1_ * 12)
                                       + (size_t)i0 * 12 + r * 4);
        *(float4*)&ls[fl][r * 4] = v;
    }
    __syncthreads();
    const int i_l = tid >> 3, f_l = (tid & 7) * 4;
    const int i = i0 + i_l, f = f0 + f_l;
    const int kc = f >> 6, within = f & 63;
    const int cc = (within >> 3) ^ (i & 7), half = (within >> 2) & 1;
    #pragma unroll
    for (int pq = 0; pq < 12; ++pq) {
        ushort4 o;
        o.x = f2bf(ls[f_l + 0][i_l * 12 + pq]);
        o.y = f2bf(ls[f_l + 1][i_l * 12 + pq]);
        o.z = f2bf(ls[f_l + 2][i_l * 12 + pq]);
        o.w = f2bf(ls[f_l + 3][i_l * 12 + pq]);
        *(ushort4*)(W1s + (size_t)(c * 12 + pq) * 65536
                        + kc * 8192 + i * 64 + cc * 8 + half * 4) = o;
    }
}

// ---------------------------------------------------------------------------
// Repack W2 (C,H1,H2,3,4) f32 -> W2b[(c*12+rs)][o][i] bf16 (unchanged)
// ---------------------------------------------------------------------------
__global__ __launch_bounds__(256) void repack_w2(const float* __restrict__ W2,
                                                 unsigned short* __restrict__ W2b) {
    __shared__ float ls[32][384];
    const int i0 = blockIdx.x * 32, o0 = blockIdx.y * 32, c = blockIdx.z;
    const int tid = threadIdx.x;
    #pragma unroll
    for (int it = 0; it < 12; ++it) {
        int idx = tid + it * 256;
        int il = idx / 96, r = idx - il * 96;
        float4 v = *(const float4*)(W2 + ((size_t)(c * H1_ + i0 + il)) * (H2_ * 12)
                                       + (size_t)o0 * 12 + r * 4);
        *(float4*)&ls[il][r * 4] = v;
    }
    __syncthreads();
    const int o_l = tid >> 3, i_l = (tid & 7) * 4;
    #pragma unroll
    for (int rs = 0; rs < 12; ++rs) {
        ushort4 o;
        o.x = f2bf(ls[i_l + 0][o_l * 12 + rs]);
        o.y = f2bf(ls[i_l + 1][o_l * 12 + rs]);
        o.z = f2bf(ls[i_l + 2][o_l * 12 + rs]);
        o.w = f2bf(ls[i_l + 3][o_l * 12 + rs]);
        *(ushort4*)(W2b + (((size_t)(c * 12 + rs)) * H2_ + o0 + o_l) * H1_ + i0 + i_l) = o;
    }
}

// ---------------------------------------------------------------------------
// Fused MFMA decoder, v9 = v8 with the W1s stride bug fixed (65536/slice,
// 8192/kc-chunk). Phase-1 = LDS double-buffered GEMM, zero-VGPR DMA staging
// of pre-swizzled images, 2-phase schedule (one barrier per K-step).
// A-tile (64x64) staged once per block, shared by 4 waves. LDS 48KB.
// Phase 2 unchanged (h1 from LDS, W2b direct from L2).
// ---------------------------------------------------------------------------
__global__ __launch_bounds__(256) void fused_mfma(
    const unsigned short* __restrict__ xTs, const unsigned short* __restrict__ W1s,
    const unsigned short* __restrict__ W2b, const int* __restrict__ cam,
    const int* __restrict__ ord,
    const float* __restrict__ b1, const float* __restrict__ b2,
    const float* __restrict__ W3, const float* __restrict__ b3,
    float* __restrict__ out)
{
    // 2 bufs x (A image 4096 ush + B image 8192 ush) = 24576 ushorts = 48 KB
    __shared__ __align__(16) unsigned short smem[24576];

    const int idx = blockIdx.x;
    const int swz = (idx & 7) * 192 + (idx >> 3);   // bijective XCD swizzle
    const int bpos = swz / 12, pq = swz - bpos * 12;
    const int b = ord[bpos];

    const int tid = threadIdx.x;
    const int w = tid >> 6, l = tid & 63;
    const int l15 = l & 15, g = l >> 4;
    const int c = cam[b];

    // ---------------- Phase 1: h1(64x128) = xT(64x512) * W1^T ----------------
    const unsigned short* xchunk = xTs + (size_t)b * 32768;          // 8 x 4096
    const unsigned short* wchunk = W1s + (size_t)(c * 12 + pq) * 65536; // 8 x 8192

    // per-wave staging: A pieces w*2..+1 (of 8), B pieces w*4..+3 (of 16)
    #define STAGE1(kc, buf)                                                       \
        {                                                                         \
            _Pragma("unroll")                                                     \
            for (int k = 0; k < 2; ++k)                                           \
                async_cp16(xchunk + (kc) * 4096 + (w * 2 + k) * 512 + l * 8,      \
                           smem + (buf) * 12288 + (w * 2 + k) * 512 + l * 8);     \
            _Pragma("unroll")                                                     \
            for (int k = 0; k < 4; ++k)                                           \
                async_cp16(wchunk + (kc) * 8192 + (w * 4 + k) * 512 + l * 8,      \
                           smem + (buf) * 12288 + 4096 + (w * 4 + k) * 512 + l * 8); \
        }

    f32x4 acc1[4][2];
    #pragma unroll
    for (int mt = 0; mt < 4; ++mt) {
        acc1[mt][0] = (f32x4){0.f, 0.f, 0.f, 0.f};
        acc1[mt][1] = (f32x4){0.f, 0.f, 0.f, 0.f};
    }

    STAGE1(0, 0);
    __syncthreads();

    const int sxor = (l15 & 7);   // XOR-swizzle key (frag rows share l15&7)
    #pragma unroll
    for (int kc = 0; kc < 8; ++kc) {
        if (kc < 7) STAGE1(kc + 1, (kc + 1) & 1);

        const int base = (kc & 1) * 12288;
        #pragma unroll
        for (int kk2 = 0; kk2 < 2; ++kk2) {
            const int cc = (kk2 * 4 + g) ^ sxor;
            short8_t af[4], bf[2];
            #pragma unroll
            for (int mt = 0; mt < 4; ++mt)
                af[mt] = *(const short8_t*)(smem + base + (16 * mt + l15) * 64 + cc * 8);
            #pragma unroll
            for (int ni = 0; ni < 2; ++ni)
                bf[ni] = *(const short8_t*)(smem + base + 4096
                                            + (32 * w + 16 * ni + l15) * 64 + cc * 8);
            #pragma unroll
            for (int mt = 0; mt < 4; ++mt)
                #pragma unroll
                for (int ni = 0; ni < 2; ++ni)
                    acc1[mt][ni] = __builtin_amdgcn_mfma_f32_16x16x32_bf16(
                        af[mt], bf[ni], acc1[mt][ni], 0, 0, 0);
        }
        __syncthreads();   // drains staging + all waves done with cur buf
    }

    // phase-2 seg-0 B prefetch before h1 writes (T14)
    const unsigned short* W2base = W2b + (size_t)(c * 12 + w * 3) * (H2_ * H1_)
                                 + (size_t)l15 * H1_ + 8 * g;
    short8_t bfr[2][4];
    #pragma unroll
    for (int kk = 0; kk < 4; ++kk)
        bfr[0][kk] = *(const short8_t*)(W2base + kk * 32);

    // bias + relu -> h1s [64][136] in smem buf0 region (8704 ush <= 12288)
    unsigned short* h1s = smem;
    #pragma unroll
    for (int ni = 0; ni < 2; ++ni) {
        const int i = 32 * w + 16 * ni + l15;
        const float b1v = b1[c * H1_ + i];
        #pragma unroll
        for (int mt = 0; mt < 4; ++mt)
            #pragma unroll
            for (int r = 0; r < 4; ++r) {
                float h = acc1[mt][ni][r] + b1v;
                h = h > 0.f ? h : 0.f;
                h1s[(16 * mt + 4 * g + r) * 136 + i] = f2bf(h);
            }
    }
    __syncthreads();

    // ---------------- Phase 2 ----------------
    short8_t a2[4][4];
    #pragma unroll
    for (int mt = 0; mt < 4; ++mt)
        #pragma unroll
        for (int kk = 0; kk < 4; ++kk)
            a2[mt][kk] = *(const short8_t*)&h1s[(16 * mt + l15) * 136 + 32 * kk + 8 * g];

    float w3v[4], b2v[4];
    #pragma unroll
    for (int nt = 0; nt < 4; ++nt) {
        w3v[nt] = W3[c * H2_ + 16 * nt + l15];
        b2v[nt] = b2[c * H2_ + 16 * nt + l15];
    }
    const float b3v = b3[c];
    const int p = pq >> 2, q = pq & 3;

    float s[4][4];
    #pragma unroll
    for (int mt = 0; mt < 4; ++mt) { s[mt][0] = s[mt][1] = s[mt][2] = s[mt][3] = 0.f; }

    // seg = 0..11 : rs_local = seg>>2, nt = seg&3
    #pragma unroll
    for (int seg = 0; seg < 12; ++seg) {
        if (seg < 11) {
            const int ns = seg + 1;
            const unsigned short* nb = W2base + (size_t)(ns >> 2) * (H2_ * H1_)
                                     + (ns & 3) * (16 * H1_);
            #pragma unroll
            for (int kk = 0; kk < 4; ++kk)
                bfr[(seg + 1) & 1][kk] = *(const short8_t*)(nb + kk * 32);
        }
        const int nt = seg & 3;
        #pragma unroll
        for (int mt = 0; mt < 4; ++mt) {
            f32x4 acc2 = (f32x4){0.f, 0.f, 0.f, 0.f};
            #pragma unroll
            for (int kk = 0; kk < 4; ++kk)
                acc2 = __builtin_amdgcn_mfma_f32_16x16x32_bf16(
                    a2[mt][kk], bfr[seg & 1][kk], acc2, 0, 0, 0);
            #pragma unroll
            for (int r = 0; r < 4; ++r)
                s[mt][r] += w3v[nt] * fmaxf(acc2[r] + b2v[nt], 0.f);
        }

        if (nt == 3) {
            const int rs = w * 3 + (seg >> 2);
            const int hrow = p * 3 + (rs >> 2), wcol = q * 4 + (rs & 3);
            #pragma unroll
            for (int mt = 0; mt < 4; ++mt)
                #pragma unroll
                for (int r = 0; r < 4; ++r) {
                    float v = s[mt][r];
                    v += __shfl_xor(v, 1); v += __shfl_xor(v, 2);
                    v += __shfl_xor(v, 4); v += __shfl_xor(v, 8);
                    if (l15 == 0) {
                        const int t = 16 * mt + 4 * g + r;
                        if (t < T_)
                            out[(((size_t)b * T_ + t) * 9 + hrow) * 16 + wcol] =
                                1.f / (1.f + __expf(-(v + b3v)));
                    }
                    s[mt][r] = 0.f;
                }
        }
    }
    #undef STAGE1
}

// ---------------------------------------------------------------------------
// fp32 VALU fallback — used only if ws too small
// ---------------------------------------------------------------------------
__global__ __launch_bounds__(256) void fused_decoder_f32(
    const float* __restrict__ x,   const int* __restrict__ cam,
    const float* __restrict__ W1,  const float* __restrict__ b1,
    const float* __restrict__ W2,  const float* __restrict__ b2,
    const float* __restrict__ W3,  const float* __restrict__ b3,
    float* __restrict__ out)
{
    __shared__ float h1s[T_ * H1_];
    __shared__ float stage[8192];

    const int pq  = blockIdx.x;
    const int b   = blockIdx.y;
    const int p   = pq >> 2, q = pq & 3;
    const int tid = threadIdx.x;
    const int c   = cam[b];

    float* xs  = stage;
    float* w1s = stage + 2048;

    const int ig = tid & 31;
    const int tg = tid >> 5;

    float acc[8][4];
    #pragma unroll
    for (int a = 0; a < 8; ++a)
        #pragma unroll
        for (int j = 0; j < 4; ++j) acc[a][j] = 0.f;

    for (int f0 = 0; f0 < F_; f0 += 32) {
        __syncthreads();
        {
            int lane = tid & 63;
            int sub  = tid >> 6;
            if (lane < T_) {
                #pragma unroll
                for (int m = 0; m < 8; ++m) {
                    int kk = sub * 8 + m;
                    xs[kk * 64 + lane] = x[((size_t)b * F_ + f0 + kk) * T_ + lane];
                }
            }
        }
        for (int e = tid; e < 32 * H1_; e += 256) {
            int kk = e >> 7, i = e & 127;
            w1s[e] = W1[(((size_t)c * F_ + f0 + kk) * H1_ + i) * 12 + pq];
        }
        __syncthreads();
        #pragma unroll 8
        for (int kk = 0; kk < 32; ++kk) {
            float4 bv = *(const float4*)&w1s[kk * 128 + ig * 4];
            float4 a0 = *(const float4*)&xs[kk * 64 + tg * 8];
            float4 a1 = *(const float4*)&xs[kk * 64 + tg * 8 + 4];
            float at[8] = {a0.x, a0.y, a0.z, a0.w, a1.x, a1.y, a1.z, a1.w};
            #pragma unroll
            for (int tt = 0; tt < 8; ++tt) {
                acc[tt][0] = fmaf(at[tt], bv.x, acc[tt][0]);
                acc[tt][1] = fmaf(at[tt], bv.y, acc[tt][1]);
                acc[tt][2] = fmaf(at[tt], bv.z, acc[tt][2]);
                acc[tt][3] = fmaf(at[tt], bv.w, acc[tt][3]);
            }
        }
    }
    {
        float4 b1v = *(const float4*)&b1[c * H1_ + ig * 4];
        #pragma unroll
        for (int tt = 0; tt < 8; ++tt) {
            int t = tg * 8 + tt;
            if (t < T_) {
                float4 hv;
                hv.x = fmaxf(acc[tt][0] + b1v.x, 0.f);
                hv.y = fmaxf(acc[tt][1] + b1v.y, 0.f);
                hv.z = fmaxf(acc[tt][2] + b1v.z, 0.f);
                hv.w = fmaxf(acc[tt][3] + b1v.w, 0.f);
                *(float4*)&h1s[t * H1_ + ig * 4] = hv;
            }
        }
    }

    const int lane = tid & 63;
    const int wv   = tid >> 6;
    const float w3v = W3[c * H2_ + lane];
    const float b2v = b2[c * H2_ + lane];
    const float b3v = b3[c];
    float* w2s = stage;

    for (int rs = 0; rs < 12; ++rs) {
        __syncthreads();
        for (int e = tid; e < H1_ * H2_; e += 256) {
            int i = e >> 6, o = e & 63;
            w2s[e] = W2[(((size_t)c * H1_ + i) * H2_ + o) * 12 + rs];
        }
        __syncthreads();

        float acc2[15];
        #pragma unroll
        for (int j = 0; j < 15; ++j) acc2[j] = 0.f;

        for (int i = 0; i < H1_; i += 4) {
            float wa = w2s[(i + 0) * 64 + lane];
            float wb = w2s[(i + 1) * 64 + lane];
            float wc = w2s[(i + 2) * 64 + lane];
            float wd = w2s[(i + 3) * 64 + lane];
            #pragma unroll
            for (int j = 0; j < 15; ++j) {
                float4 h = *(const float4*)&h1s[(wv * 15 + j) * H1_ + i];
                acc2[j] = fmaf(h.x, wa, acc2[j]);
                acc2[j] = fmaf(h.y, wb, acc2[j]);
                acc2[j] = fmaf(h.z, wc, acc2[j]);
                acc2[j] = fmaf(h.w, wd, acc2[j]);
            }
        }

        const int r = rs >> 2, s = rs & 3;
        const int hrow = p * 3 + r, wcol = q * 4 + s;
        #pragma unroll
        for (int j = 0; j < 15; ++j) {
            float y = w3v * fmaxf(acc2[j] + b2v, 0.f);
            #pragma unroll
            for (int m = 32; m > 0; m >>= 1) y += __shfl_xor(y, m, 64);
            if (lane == j) {
                int t = wv * 15 + j;
                float v = y + b3v;
                out[(((size_t)b * T_ + t) * 9 + hrow) * 16 + wcol] = 1.f / (1.f + __expf(-v));
            }
        }
    }
}

// ---------------------------------------------------------------------------
extern "C" void kernel_launch(void* const* d_in, const int* in_sizes, int n_in,
                              void* d_out, int out_size, void* d_ws, size_t ws_size,
                              hipStream_t stream) {
    const float* x   = (const float*)d_in[0];
    const int*   cam = (const int*)  d_in[1];
    const float* W1  = (const float*)d_in[2];
    const float* b1  = (const float*)d_in[3];
    const float* W2  = (const float*)d_in[4];
    const float* b2  = (const float*)d_in[5];
    const float* W3  = (const float*)d_in[6];
    const float* b3  = (const float*)d_in[7];
    float* outp = (float*)d_out;

    const size_t n_xT  = (size_t)B_ * 32768;            //  4,194,304 (swizzled A images)
    const size_t n_w1b = (size_t)C_ * 12 * 65536;       // 11,796,480 (swizzled B images)
    const size_t n_w2b = (size_t)C_ * 12 * H2_ * H1_;   //  1,474,560
    const size_t needed = (n_xT + n_w1b + n_w2b) * sizeof(unsigned short)
                        + B_ * sizeof(int);

    if (d_ws != nullptr && ws_size >= needed) {
        unsigned short* xTs = (unsigned short*)d_ws;
        unsigned short* W1p = xTs + n_xT;
        unsigned short* W2p = W1p + n_w1b;
        int* ord = (int*)(W2p + n_w2b);
        make_order<<<1, 128, 0, stream>>>(cam, ord);
        repack_x <<<dim3(4, B_), 256, 0, stream>>>(x, xTs);
        repack_w1<<<dim3(F_ / 32, H1_ / 32, C_), 256, 0, stream>>>(W1, W1p);
        repack_w2<<<dim3(H1_ / 32, H2_ / 32, C_), 256, 0, stream>>>(W2, W2p);
        fused_mfma<<<dim3(12 * B_), 256, 0, stream>>>(
            xTs, W1p, W2p, cam, ord, b1, b2, W3, b3, outp);
    } else {
        fused_decoder_f32<<<dim3(12, B_), 256, 0, stream>>>(
            x, cam, W1, b1, W2, b2, W3, b3, outp);
    }
}

// Round 10
// 103.633 us; speedup vs baseline: 2.2278x; 1.0080x over previous
//
#include <hip/hip_runtime.h>
#include <hip/hip_bf16.h>
#include <cstdint>

// Problem constants
#define B_  128
#define F_  512
#define T_  60
#define C_  15
#define H1_ 128
#define H2_ 64

typedef short short8_t __attribute__((ext_vector_type(8)));   // 8 bf16 (4 VGPR)
typedef float f32x4    __attribute__((ext_vector_type(4)));   // MFMA acc

static __device__ __forceinline__ unsigned short f2bf(float f) {
    union { float f; uint32_t u; } v; v.f = f;
    uint32_t r = v.u + 0x7FFF + ((v.u >> 16) & 1);   // RNE
    return (unsigned short)(r >> 16);
}

// async 16B global -> LDS DMA (dest = wave-uniform base + lane*16)
static __device__ __forceinline__ void async_cp16(const unsigned short* g, unsigned short* l) {
    __builtin_amdgcn_global_load_lds(
        (const __attribute__((address_space(1))) unsigned int*)g,
        (__attribute__((address_space(3))) unsigned int*)l, 16, 0, 0);
}

// ---------------------------------------------------------------------------
// Camera-sort: ord[rank] = b, stable sort of b by cam[b]. 1 block, 128 thr.
// ---------------------------------------------------------------------------
__global__ __launch_bounds__(128) void make_order(const int* __restrict__ cam,
                                                  int* __restrict__ ord) {
    __shared__ int cs[B_];
    const int b = threadIdx.x;
    cs[b] = cam[b];
    __syncthreads();
    const int cb = cs[b];
    int rank = 0;
    #pragma unroll 16
    for (int j = 0; j < B_; ++j) {
        int cj = cs[j];
        rank += (cj < cb || (cj == cb && j < b)) ? 1 : 0;
    }
    ord[rank] = b;
}

// ---------------------------------------------------------------------------
// Repack x (B,F,T) f32 -> xTs (B, 8 kc-chunks, swizzled 64x64 LDS image) bf16.
// Image unit layout (16B units): chunk kc (stride 4096 ush), row t (0..63,
//   zero-pad t>=60), unit col cc (0..7): holds k = kc*64 + (cc ^ (t&7))*8..+8
//   (XOR swizzle baked in: LINEAR global_load_lds -> swizzled LDS tile).
// grid (4 f-chunks of 128, B)
// ---------------------------------------------------------------------------
__global__ __launch_bounds__(256) void repack_x(const float* __restrict__ x,
                                                unsigned short* __restrict__ xTs) {
    __shared__ float xs[128][61];
    const int f0 = blockIdx.x * 128, b = blockIdx.y, tid = threadIdx.x;
    #pragma unroll
    for (int it = 0; it < 32; ++it) {
        int idx = tid + it * 256;          // 128*64
        int fl = idx >> 6, t = idx & 63;
        if (t < T_) xs[fl][t] = x[((size_t)b * F_ + f0 + fl) * T_ + t];
    }
    __syncthreads();
    #pragma unroll
    for (int it = 0; it < 8; ++it) {
        int idx = tid + it * 256;          // 64*32
        int t = idx >> 5, f4 = (idx & 31) * 4;
        ushort4 o;
        o.x = (t < T_) ? f2bf(xs[f4 + 0][t]) : 0;
        o.y = (t < T_) ? f2bf(xs[f4 + 1][t]) : 0;
        o.z = (t < T_) ? f2bf(xs[f4 + 2][t]) : 0;
        o.w = (t < T_) ? f2bf(xs[f4 + 3][t]) : 0;
        const int f = f0 + f4;
        const int kc = f >> 6, within = f & 63;
        const int cc = (within >> 3) ^ (t & 7), half = (within >> 2) & 1;
        *(ushort4*)(xTs + (size_t)b * 32768 + kc * 4096 + t * 64 + cc * 8 + half * 4) = o;
    }
}

// ---------------------------------------------------------------------------
// Repack W1 (C,F,H1,3,4) f32 -> W1s[(c*12+pq)][kc][swizzled 128x64 image] bf16
//   per-(c,pq) slice = 65536 ush (128 rows x 512 k); per-kc chunk = 8192 ush.
//   unit (kc, row i, cc): holds k = kc*64 + (cc ^ (i&7))*8 .. +8
// ---------------------------------------------------------------------------
__global__ __launch_bounds__(256) void repack_w1(const float* __restrict__ W1,
                                                 unsigned short* __restrict__ W1s) {
    __shared__ float ls[32][384];
    const int f0 = blockIdx.x * 32, i0 = blockIdx.y * 32, c = blockIdx.z;
    const int tid = threadIdx.x;
    #pragma unroll
    for (int it = 0; it < 12; ++it) {
        int idx = tid + it * 256;              // 3072 float4
        int fl = idx / 96, r = idx - fl * 96;
        float4 v = *(const float4*)(W1 + ((size_t)(c * F_ + f0 + fl)) * (H1_ * 12)
                                       + (size_t)i0 * 12 + r * 4);
        *(float4*)&ls[fl][r * 4] = v;
    }
    __syncthreads();
    const int i_l = tid >> 3, f_l = (tid & 7) * 4;
    const int i = i0 + i_l, f = f0 + f_l;
    const int kc = f >> 6, within = f & 63;
    const int cc = (within >> 3) ^ (i & 7), half = (within >> 2) & 1;
    #pragma unroll
    for (int pq = 0; pq < 12; ++pq) {
        ushort4 o;
        o.x = f2bf(ls[f_l + 0][i_l * 12 + pq]);
        o.y = f2bf(ls[f_l + 1][i_l * 12 + pq]);
        o.z = f2bf(ls[f_l + 2][i_l * 12 + pq]);
        o.w = f2bf(ls[f_l + 3][i_l * 12 + pq]);
        *(ushort4*)(W1s + (size_t)(c * 12 + pq) * 65536
                        + kc * 8192 + i * 64 + cc * 8 + half * 4) = o;
    }
}

// ---------------------------------------------------------------------------
// Repack W2 (C,H1,H2,3,4) f32 -> W2b[(c*12+rs)][o][i] bf16 (unchanged)
// ---------------------------------------------------------------------------
__global__ __launch_bounds__(256) void repack_w2(const float* __restrict__ W2,
                                                 unsigned short* __restrict__ W2b) {
    __shared__ float ls[32][384];
    const int i0 = blockIdx.x * 32, o0 = blockIdx.y * 32, c = blockIdx.z;
    const int tid = threadIdx.x;
    #pragma unroll
    for (int it = 0; it < 12; ++it) {
        int idx = tid + it * 256;
        int il = idx / 96, r = idx - il * 96;
        float4 v = *(const float4*)(W2 + ((size_t)(c * H1_ + i0 + il)) * (H2_ * 12)
                                       + (size_t)o0 * 12 + r * 4);
        *(float4*)&ls[il][r * 4] = v;
    }
    __syncthreads();
    const int o_l = tid >> 3, i_l = (tid & 7) * 4;
    #pragma unroll
    for (int rs = 0; rs < 12; ++rs) {
        ushort4 o;
        o.x = f2bf(ls[i_l + 0][o_l * 12 + rs]);
        o.y = f2bf(ls[i_l + 1][o_l * 12 + rs]);
        o.z = f2bf(ls[i_l + 2][o_l * 12 + rs]);
        o.w = f2bf(ls[i_l + 3][o_l * 12 + rs]);
        *(ushort4*)(W2b + (((size_t)(c * 12 + rs)) * H2_ + o0 + o_l) * H1_ + i0 + i_l) = o;
    }
}

// ---------------------------------------------------------------------------
// Fused MFMA decoder, v10 = v9 with counted-vmcnt K-loop (T4): the per-kc
// __syncthreads() forced a vmcnt(0) drain of freshly-issued staging every
// step (~300-500 cy dead/step). Now: prologue stages kc=0,1; each iter waits
// vmcnt(6) (own 6 loads of kc landed; kc+1's 6 still in flight), raw
// s_barrier, read+MFMA, raw s_barrier, restage kc+2. Only the last iter
// drains to 0. Cross-wave: every wave vmcnt-waits before bar1; MFMA reg deps
// force lgkmcnt drain before bar2 (no read/restage race).
// Phase 2 unchanged (h1 from LDS, W2b direct from L2, 1-ahead prefetch).
// ---------------------------------------------------------------------------
__global__ __launch_bounds__(256) void fused_mfma(
    const unsigned short* __restrict__ xTs, const unsigned short* __restrict__ W1s,
    const unsigned short* __restrict__ W2b, const int* __restrict__ cam,
    const int* __restrict__ ord,
    const float* __restrict__ b1, const float* __restrict__ b2,
    const float* __restrict__ W3, const float* __restrict__ b3,
    float* __restrict__ out)
{
    // 2 bufs x (A image 4096 ush + B image 8192 ush) = 24576 ushorts = 48 KB
    __shared__ __align__(16) unsigned short smem[24576];

    const int idx = blockIdx.x;
    const int swz = (idx & 7) * 192 + (idx >> 3);   // bijective XCD swizzle
    const int bpos = swz / 12, pq = swz - bpos * 12;
    const int b = ord[bpos];

    const int tid = threadIdx.x;
    const int w = tid >> 6, l = tid & 63;
    const int l15 = l & 15, g = l >> 4;
    const int c = cam[b];

    // ---------------- Phase 1: h1(64x128) = xT(64x512) * W1^T ----------------
    const unsigned short* xchunk = xTs + (size_t)b * 32768;             // 8 x 4096
    const unsigned short* wchunk = W1s + (size_t)(c * 12 + pq) * 65536; // 8 x 8192

    // per-wave staging: A pieces w*2..+1 (of 8), B pieces w*4..+3 (of 16)
    // exactly 6 async ops per wave per STAGE1 -> vmcnt accounting unit = 6
    #define STAGE1(kc, buf)                                                       \
        {                                                                         \
            _Pragma("unroll")                                                     \
            for (int k = 0; k < 2; ++k)                                           \
                async_cp16(xchunk + (kc) * 4096 + (w * 2 + k) * 512 + l * 8,      \
                           smem + (buf) * 12288 + (w * 2 + k) * 512 + l * 8);     \
            _Pragma("unroll")                                                     \
            for (int k = 0; k < 4; ++k)                                           \
                async_cp16(wchunk + (kc) * 8192 + (w * 4 + k) * 512 + l * 8,      \
                           smem + (buf) * 12288 + 4096 + (w * 4 + k) * 512 + l * 8); \
        }

    f32x4 acc1[4][2];
    #pragma unroll
    for (int mt = 0; mt < 4; ++mt) {
        acc1[mt][0] = (f32x4){0.f, 0.f, 0.f, 0.f};
        acc1[mt][1] = (f32x4){0.f, 0.f, 0.f, 0.f};
    }

    STAGE1(0, 0);
    STAGE1(1, 1);

    const int sxor = (l15 & 7);   // XOR-swizzle key (frag rows share l15&7)
    #pragma unroll
    for (int kc = 0; kc < 8; ++kc) {
        // counted wait: kc's 6 loads landed; kc+1's (6 newer) may stay in flight
        if (kc < 7) { asm volatile("s_waitcnt vmcnt(6)" ::: "memory"); }
        else        { asm volatile("s_waitcnt vmcnt(0)" ::: "memory"); }
        __builtin_amdgcn_s_barrier();
        asm volatile("" ::: "memory");   // pin ds_reads below the barrier

        const int base = (kc & 1) * 12288;
        #pragma unroll
        for (int kk2 = 0; kk2 < 2; ++kk2) {
            const int cc = (kk2 * 4 + g) ^ sxor;
            short8_t af[4], bf[2];
            #pragma unroll
            for (int mt = 0; mt < 4; ++mt)
                af[mt] = *(const short8_t*)(smem + base + (16 * mt + l15) * 64 + cc * 8);
            #pragma unroll
            for (int ni = 0; ni < 2; ++ni)
                bf[ni] = *(const short8_t*)(smem + base + 4096
                                            + (32 * w + 16 * ni + l15) * 64 + cc * 8);
            #pragma unroll
            for (int mt = 0; mt < 4; ++mt)
                #pragma unroll
                for (int ni = 0; ni < 2; ++ni)
                    acc1[mt][ni] = __builtin_amdgcn_mfma_f32_16x16x32_bf16(
                        af[mt], bf[ni], acc1[mt][ni], 0, 0, 0);
        }

        asm volatile("" ::: "memory");   // reads consumed (lgkm drained via MFMA deps)
        __builtin_amdgcn_s_barrier();    // all waves done with buf[kc&1]
        if (kc < 6) STAGE1(kc + 2, kc & 1);
    }

    // phase-2 seg-0 B prefetch before h1 writes (T14)
    const unsigned short* W2base = W2b + (size_t)(c * 12 + w * 3) * (H2_ * H1_)
                                 + (size_t)l15 * H1_ + 8 * g;
    short8_t bfr[2][4];
    #pragma unroll
    for (int kk = 0; kk < 4; ++kk)
        bfr[0][kk] = *(const short8_t*)(W2base + kk * 32);

    // bias + relu -> h1s [64][136] in smem buf0 region (8704 ush <= 12288)
    unsigned short* h1s = smem;
    #pragma unroll
    for (int ni = 0; ni < 2; ++ni) {
        const int i = 32 * w + 16 * ni + l15;
        const float b1v = b1[c * H1_ + i];
        #pragma unroll
        for (int mt = 0; mt < 4; ++mt)
            #pragma unroll
            for (int r = 0; r < 4; ++r) {
                float h = acc1[mt][ni][r] + b1v;
                h = h > 0.f ? h : 0.f;
                h1s[(16 * mt + 4 * g + r) * 136 + i] = f2bf(h);
            }
    }
    __syncthreads();

    // ---------------- Phase 2 ----------------
    short8_t a2[4][4];
    #pragma unroll
    for (int mt = 0; mt < 4; ++mt)
        #pragma unroll
        for (int kk = 0; kk < 4; ++kk)
            a2[mt][kk] = *(const short8_t*)&h1s[(16 * mt + l15) * 136 + 32 * kk + 8 * g];

    float w3v[4], b2v[4];
    #pragma unroll
    for (int nt = 0; nt < 4; ++nt) {
        w3v[nt] = W3[c * H2_ + 16 * nt + l15];
        b2v[nt] = b2[c * H2_ + 16 * nt + l15];
    }
    const float b3v = b3[c];
    const int p = pq >> 2, q = pq & 3;

    float s[4][4];
    #pragma unroll
    for (int mt = 0; mt < 4; ++mt) { s[mt][0] = s[mt][1] = s[mt][2] = s[mt][3] = 0.f; }

    // seg = 0..11 : rs_local = seg>>2, nt = seg&3
    #pragma unroll
    for (int seg = 0; seg < 12; ++seg) {
        if (seg < 11) {
            const int ns = seg + 1;
            const unsigned short* nb = W2base + (size_t)(ns >> 2) * (H2_ * H1_)
                                     + (ns & 3) * (16 * H1_);
            #pragma unroll
            for (int kk = 0; kk < 4; ++kk)
                bfr[(seg + 1) & 1][kk] = *(const short8_t*)(nb + kk * 32);
        }
        const int nt = seg & 3;
        #pragma unroll
        for (int mt = 0; mt < 4; ++mt) {
            f32x4 acc2 = (f32x4){0.f, 0.f, 0.f, 0.f};
            #pragma unroll
            for (int kk = 0; kk < 4; ++kk)
                acc2 = __builtin_amdgcn_mfma_f32_16x16x32_bf16(
                    a2[mt][kk], bfr[seg & 1][kk], acc2, 0, 0, 0);
            #pragma unroll
            for (int r = 0; r < 4; ++r)
                s[mt][r] += w3v[nt] * fmaxf(acc2[r] + b2v[nt], 0.f);
        }

        if (nt == 3) {
            const int rs = w * 3 + (seg >> 2);
            const int hrow = p * 3 + (rs >> 2), wcol = q * 4 + (rs & 3);
            #pragma unroll
            for (int mt = 0; mt < 4; ++mt)
                #pragma unroll
                for (int r = 0; r < 4; ++r) {
                    float v = s[mt][r];
                    v += __shfl_xor(v, 1); v += __shfl_xor(v, 2);
                    v += __shfl_xor(v, 4); v += __shfl_xor(v, 8);
                    if (l15 == 0) {
                        const int t = 16 * mt + 4 * g + r;
                        if (t < T_)
                            out[(((size_t)b * T_ + t) * 9 + hrow) * 16 + wcol] =
                                1.f / (1.f + __expf(-(v + b3v)));
                    }
                    s[mt][r] = 0.f;
                }
        }
    }
    #undef STAGE1
}

// ---------------------------------------------------------------------------
// fp32 VALU fallback — used only if ws too small
// ---------------------------------------------------------------------------
__global__ __launch_bounds__(256) void fused_decoder_f32(
    const float* __restrict__ x,   const int* __restrict__ cam,
    const float* __restrict__ W1,  const float* __restrict__ b1,
    const float* __restrict__ W2,  const float* __restrict__ b2,
    const float* __restrict__ W3,  const float* __restrict__ b3,
    float* __restrict__ out)
{
    __shared__ float h1s[T_ * H1_];
    __shared__ float stage[8192];

    const int pq  = blockIdx.x;
    const int b   = blockIdx.y;
    const int p   = pq >> 2, q = pq & 3;
    const int tid = threadIdx.x;
    const int c   = cam[b];

    float* xs  = stage;
    float* w1s = stage + 2048;

    const int ig = tid & 31;
    const int tg = tid >> 5;

    float acc[8][4];
    #pragma unroll
    for (int a = 0; a < 8; ++a)
        #pragma unroll
        for (int j = 0; j < 4; ++j) acc[a][j] = 0.f;

    for (int f0 = 0; f0 < F_; f0 += 32) {
        __syncthreads();
        {
            int lane = tid & 63;
            int sub  = tid >> 6;
            if (lane < T_) {
                #pragma unroll
                for (int m = 0; m < 8; ++m) {
                    int kk = sub * 8 + m;
                    xs[kk * 64 + lane] = x[((size_t)b * F_ + f0 + kk) * T_ + lane];
                }
            }
        }
        for (int e = tid; e < 32 * H1_; e += 256) {
            int kk = e >> 7, i = e & 127;
            w1s[e] = W1[(((size_t)c * F_ + f0 + kk) * H1_ + i) * 12 + pq];
        }
        __syncthreads();
        #pragma unroll 8
        for (int kk = 0; kk < 32; ++kk) {
            float4 bv = *(const float4*)&w1s[kk * 128 + ig * 4];
            float4 a0 = *(const float4*)&xs[kk * 64 + tg * 8];
            float4 a1 = *(const float4*)&xs[kk * 64 + tg * 8 + 4];
            float at[8] = {a0.x, a0.y, a0.z, a0.w, a1.x, a1.y, a1.z, a1.w};
            #pragma unroll
            for (int tt = 0; tt < 8; ++tt) {
                acc[tt][0] = fmaf(at[tt], bv.x, acc[tt][0]);
                acc[tt][1] = fmaf(at[tt], bv.y, acc[tt][1]);
                acc[tt][2] = fmaf(at[tt], bv.z, acc[tt][2]);
                acc[tt][3] = fmaf(at[tt], bv.w, acc[tt][3]);
            }
        }
    }
    {
        float4 b1v = *(const float4*)&b1[c * H1_ + ig * 4];
        #pragma unroll
        for (int tt = 0; tt < 8; ++tt) {
            int t = tg * 8 + tt;
            if (t < T_) {
                float4 hv;
                hv.x = fmaxf(acc[tt][0] + b1v.x, 0.f);
                hv.y = fmaxf(acc[tt][1] + b1v.y, 0.f);
                hv.z = fmaxf(acc[tt][2] + b1v.z, 0.f);
                hv.w = fmaxf(acc[tt][3] + b1v.w, 0.f);
                *(float4*)&h1s[t * H1_ + ig * 4] = hv;
            }
        }
    }

    const int lane = tid & 63;
    const int wv   = tid >> 6;
    const float w3v = W3[c * H2_ + lane];
    const float b2v = b2[c * H2_ + lane];
    const float b3v = b3[c];
    float* w2s = stage;

    for (int rs = 0; rs < 12; ++rs) {
        __syncthreads();
        for (int e = tid; e < H1_ * H2_; e += 256) {
            int i = e >> 6, o = e & 63;
            w2s[e] = W2[(((size_t)c * H1_ + i) * H2_ + o) * 12 + rs];
        }
        __syncthreads();

        float acc2[15];
        #pragma unroll
        for (int j = 0; j < 15; ++j) acc2[j] = 0.f;

        for (int i = 0; i < H1_; i += 4) {
            float wa = w2s[(i + 0) * 64 + lane];
            float wb = w2s[(i + 1) * 64 + lane];
            float wc = w2s[(i + 2) * 64 + lane];
            float wd = w2s[(i + 3) * 64 + lane];
            #pragma unroll
            for (int j = 0; j < 15; ++j) {
                float4 h = *(const float4*)&h1s[(wv * 15 + j) * H1_ + i];
                acc2[j] = fmaf(h.x, wa, acc2[j]);
                acc2[j] = fmaf(h.y, wb, acc2[j]);
                acc2[j] = fmaf(h.z, wc, acc2[j]);
                acc2[j] = fmaf(h.w, wd, acc2[j]);
            }
        }

        const int r = rs >> 2, s = rs & 3;
        const int hrow = p * 3 + r, wcol = q * 4 + s;
        #pragma unroll
        for (int j = 0; j < 15; ++j) {
            float y = w3v * fmaxf(acc2[j] + b2v, 0.f);
            #pragma unroll
            for (int m = 32; m > 0; m >>= 1) y += __shfl_xor(y, m, 64);
            if (lane == j) {
                int t = wv * 15 + j;
                float v = y + b3v;
                out[(((size_t)b * T_ + t) * 9 + hrow) * 16 + wcol] = 1.f / (1.f + __expf(-v));
            }
        }
    }
}

// ---------------------------------------------------------------------------
extern "C" void kernel_launch(void* const* d_in, const int* in_sizes, int n_in,
                              void* d_out, int out_size, void* d_ws, size_t ws_size,
                              hipStream_t stream) {
    const float* x   = (const float*)d_in[0];
    const int*   cam = (const int*)  d_in[1];
    const float* W1  = (const float*)d_in[2];
    const float* b1  = (const float*)d_in[3];
    const float* W2  = (const float*)d_in[4];
    const float* b2  = (const float*)d_in[5];
    const float* W3  = (const float*)d_in[6];
    const float* b3  = (const float*)d_in[7];
    float* outp = (float*)d_out;

    const size_t n_xT  = (size_t)B_ * 32768;            //  4,194,304 (swizzled A images)
    const size_t n_w1b = (size_t)C_ * 12 * 65536;       // 11,796,480 (swizzled B images)
    const size_t n_w2b = (size_t)C_ * 12 * H2_ * H1_;   //  1,474,560
    const size_t needed = (n_xT + n_w1b + n_w2b) * sizeof(unsigned short)
                        + B_ * sizeof(int);

    if (d_ws != nullptr && ws_size >= needed) {
        unsigned short* xTs = (unsigned short*)d_ws;
        unsigned short* W1p = xTs + n_xT;
        unsigned short* W2p = W1p + n_w1b;
        int* ord = (int*)(W2p + n_w2b);
        make_order<<<1, 128, 0, stream>>>(cam, ord);
        repack_x <<<dim3(4, B_), 256, 0, stream>>>(x, xTs);
        repack_w1<<<dim3(F_ / 32, H1_ / 32, C_), 256, 0, stream>>>(W1, W1p);
        repack_w2<<<dim3(H1_ / 32, H2_ / 32, C_), 256, 0, stream>>>(W2, W2p);
        fused_mfma<<<dim3(12 * B_), 256, 0, stream>>>(
            xTs, W1p, W2p, cam, ord, b1, b2, W3, b3, outp);
    } else {
        fused_decoder_f32<<<dim3(12, B_), 256, 0, stream>>>(
            x, cam, W1, b1, W2, b2, W3, b3, outp);
    }
}

// Round 11
// 103.544 us; speedup vs baseline: 2.2297x; 1.0009x over previous
//
#include <hip/hip_runtime.h>
#include <hip/hip_bf16.h>
#include <cstdint>

// Problem constants
#define B_  128
#define F_  512
#define T_  60
#define C_  15
#define H1_ 128
#define H2_ 64

typedef short short8_t __attribute__((ext_vector_type(8)));   // 8 bf16 (4 VGPR)
typedef float f32x4    __attribute__((ext_vector_type(4)));   // MFMA acc

static __device__ __forceinline__ unsigned short f2bf(float f) {
    union { float f; uint32_t u; } v; v.f = f;
    uint32_t r = v.u + 0x7FFF + ((v.u >> 16) & 1);   // RNE
    return (unsigned short)(r >> 16);
}

// async 16B global -> LDS DMA (dest = wave-uniform base + lane*16)
static __device__ __forceinline__ void async_cp16(const unsigned short* g, unsigned short* l) {
    __builtin_amdgcn_global_load_lds(
        (const __attribute__((address_space(1))) unsigned int*)g,
        (__attribute__((address_space(3))) unsigned int*)l, 16, 0, 0);
}

// ---------------------------------------------------------------------------
// Camera-sort: ord[rank] = b, stable sort of b by cam[b]. 1 block, 128 thr.
// ---------------------------------------------------------------------------
__global__ __launch_bounds__(128) void make_order(const int* __restrict__ cam,
                                                  int* __restrict__ ord) {
    __shared__ int cs[B_];
    const int b = threadIdx.x;
    cs[b] = cam[b];
    __syncthreads();
    const int cb = cs[b];
    int rank = 0;
    #pragma unroll 16
    for (int j = 0; j < B_; ++j) {
        int cj = cs[j];
        rank += (cj < cb || (cj == cb && j < b)) ? 1 : 0;
    }
    ord[rank] = b;
}

// ---------------------------------------------------------------------------
// Repack x (B,F,T) f32 -> xTs (B, 8 kc-chunks, swizzled 64x64 LDS image) bf16.
// Image unit layout (16B units): chunk kc (stride 4096 ush), row t (0..63,
//   zero-pad t>=60), unit col cc (0..7): holds k = kc*64 + (cc ^ (t&7))*8..+8
//   (XOR swizzle baked in: LINEAR global_load_lds -> swizzled LDS tile).
// grid (4 f-chunks of 128, B)
// ---------------------------------------------------------------------------
__global__ __launch_bounds__(256) void repack_x(const float* __restrict__ x,
                                                unsigned short* __restrict__ xTs) {
    __shared__ float xs[128][61];
    const int f0 = blockIdx.x * 128, b = blockIdx.y, tid = threadIdx.x;
    #pragma unroll
    for (int it = 0; it < 32; ++it) {
        int idx = tid + it * 256;          // 128*64
        int fl = idx >> 6, t = idx & 63;
        if (t < T_) xs[fl][t] = x[((size_t)b * F_ + f0 + fl) * T_ + t];
    }
    __syncthreads();
    #pragma unroll
    for (int it = 0; it < 8; ++it) {
        int idx = tid + it * 256;          // 64*32
        int t = idx >> 5, f4 = (idx & 31) * 4;
        ushort4 o;
        o.x = (t < T_) ? f2bf(xs[f4 + 0][t]) : 0;
        o.y = (t < T_) ? f2bf(xs[f4 + 1][t]) : 0;
        o.z = (t < T_) ? f2bf(xs[f4 + 2][t]) : 0;
        o.w = (t < T_) ? f2bf(xs[f4 + 3][t]) : 0;
        const int f = f0 + f4;
        const int kc = f >> 6, within = f & 63;
        const int cc = (within >> 3) ^ (t & 7), half = (within >> 2) & 1;
        *(ushort4*)(xTs + (size_t)b * 32768 + kc * 4096 + t * 64 + cc * 8 + half * 4) = o;
    }
}

// ---------------------------------------------------------------------------
// Repack W1 (C,F,H1,3,4) f32 -> W1s[(c*12+pq)][kc][swizzled 128x64 image] bf16
//   per-(c,pq) slice = 65536 ush (128 rows x 512 k); per-kc chunk = 8192 ush.
//   unit (kc, row i, cc): holds k = kc*64 + (cc ^ (i&7))*8 .. +8
// ---------------------------------------------------------------------------
__global__ __launch_bounds__(256) void repack_w1(const float* __restrict__ W1,
                                                 unsigned short* __restrict__ W1s) {
    __shared__ float ls[32][384];
    const int f0 = blockIdx.x * 32, i0 = blockIdx.y * 32, c = blockIdx.z;
    const int tid = threadIdx.x;
    #pragma unroll
    for (int it = 0; it < 12; ++it) {
        int idx = tid + it * 256;              // 3072 float4
        int fl = idx / 96, r = idx - fl * 96;
        float4 v = *(const float4*)(W1 + ((size_t)(c * F_ + f0 + fl)) * (H1_ * 12)
                                       + (size_t)i0 * 12 + r * 4);
        *(float4*)&ls[fl][r * 4] = v;
    }
    __syncthreads();
    const int i_l = tid >> 3, f_l = (tid & 7) * 4;
    const int i = i0 + i_l, f = f0 + f_l;
    const int kc = f >> 6, within = f & 63;
    const int cc = (within >> 3) ^ (i & 7), half = (within >> 2) & 1;
    #pragma unroll
    for (int pq = 0; pq < 12; ++pq) {
        ushort4 o;
        o.x = f2bf(ls[f_l + 0][i_l * 12 + pq]);
        o.y = f2bf(ls[f_l + 1][i_l * 12 + pq]);
        o.z = f2bf(ls[f_l + 2][i_l * 12 + pq]);
        o.w = f2bf(ls[f_l + 3][i_l * 12 + pq]);
        *(ushort4*)(W1s + (size_t)(c * 12 + pq) * 65536
                        + kc * 8192 + i * 64 + cc * 8 + half * 4) = o;
    }
}

// ---------------------------------------------------------------------------
// Repack W2 (C,H1,H2,3,4) f32 -> W2b[(c*12+rs)][o][i] bf16 (unchanged)
// ---------------------------------------------------------------------------
__global__ __launch_bounds__(256) void repack_w2(const float* __restrict__ W2,
                                                 unsigned short* __restrict__ W2b) {
    __shared__ float ls[32][384];
    const int i0 = blockIdx.x * 32, o0 = blockIdx.y * 32, c = blockIdx.z;
    const int tid = threadIdx.x;
    #pragma unroll
    for (int it = 0; it < 12; ++it) {
        int idx = tid + it * 256;
        int il = idx / 96, r = idx - il * 96;
        float4 v = *(const float4*)(W2 + ((size_t)(c * H1_ + i0 + il)) * (H2_ * 12)
                                       + (size_t)o0 * 12 + r * 4);
        *(float4*)&ls[il][r * 4] = v;
    }
    __syncthreads();
    const int o_l = tid >> 3, i_l = (tid & 7) * 4;
    #pragma unroll
    for (int rs = 0; rs < 12; ++rs) {
        ushort4 o;
        o.x = f2bf(ls[i_l + 0][o_l * 12 + rs]);
        o.y = f2bf(ls[i_l + 1][o_l * 12 + rs]);
        o.z = f2bf(ls[i_l + 2][o_l * 12 + rs]);
        o.w = f2bf(ls[i_l + 3][o_l * 12 + rs]);
        *(ushort4*)(W2b + (((size_t)(c * 12 + rs)) * H2_ + o0 + o_l) * H1_ + i0 + i_l) = o;
    }
}

// ---------------------------------------------------------------------------
// Fused MFMA decoder, v11 = v10 with DEEP phase-2 prefetch (3 segs ahead,
// 4-slot rotation, 12 loads in flight/wave). R9->R10 showed phase-1 sync is
// not the critical path; the remaining stall model is loaded-L2 latency
// (~800-1000cy) vs phase-2's old 1-ahead slack (~175cy/seg). Now each seg's
// fragments were issued 3 seg-bodies earlier. Segs 0-2 issue before the
// h1-store barrier (hidden under epilogue + a2 hoist).
// Phase 1 unchanged from v10 (counted vmcnt, 2-deep LDS staging).
// ---------------------------------------------------------------------------
__global__ __launch_bounds__(256) void fused_mfma(
    const unsigned short* __restrict__ xTs, const unsigned short* __restrict__ W1s,
    const unsigned short* __restrict__ W2b, const int* __restrict__ cam,
    const int* __restrict__ ord,
    const float* __restrict__ b1, const float* __restrict__ b2,
    const float* __restrict__ W3, const float* __restrict__ b3,
    float* __restrict__ out)
{
    // 2 bufs x (A image 4096 ush + B image 8192 ush) = 24576 ushorts = 48 KB
    __shared__ __align__(16) unsigned short smem[24576];

    const int idx = blockIdx.x;
    const int swz = (idx & 7) * 192 + (idx >> 3);   // bijective XCD swizzle
    const int bpos = swz / 12, pq = swz - bpos * 12;
    const int b = ord[bpos];

    const int tid = threadIdx.x;
    const int w = tid >> 6, l = tid & 63;
    const int l15 = l & 15, g = l >> 4;
    const int c = cam[b];

    // ---------------- Phase 1: h1(64x128) = xT(64x512) * W1^T ----------------
    const unsigned short* xchunk = xTs + (size_t)b * 32768;             // 8 x 4096
    const unsigned short* wchunk = W1s + (size_t)(c * 12 + pq) * 65536; // 8 x 8192

    // per-wave staging: A pieces w*2..+1 (of 8), B pieces w*4..+3 (of 16)
    // exactly 6 async ops per wave per STAGE1 -> vmcnt accounting unit = 6
    #define STAGE1(kc, buf)                                                       \
        {                                                                         \
            _Pragma("unroll")                                                     \
            for (int k = 0; k < 2; ++k)                                           \
                async_cp16(xchunk + (kc) * 4096 + (w * 2 + k) * 512 + l * 8,      \
                           smem + (buf) * 12288 + (w * 2 + k) * 512 + l * 8);     \
            _Pragma("unroll")                                                     \
            for (int k = 0; k < 4; ++k)                                           \
                async_cp16(wchunk + (kc) * 8192 + (w * 4 + k) * 512 + l * 8,      \
                           smem + (buf) * 12288 + 4096 + (w * 4 + k) * 512 + l * 8); \
        }

    f32x4 acc1[4][2];
    #pragma unroll
    for (int mt = 0; mt < 4; ++mt) {
        acc1[mt][0] = (f32x4){0.f, 0.f, 0.f, 0.f};
        acc1[mt][1] = (f32x4){0.f, 0.f, 0.f, 0.f};
    }

    STAGE1(0, 0);
    STAGE1(1, 1);

    const int sxor = (l15 & 7);   // XOR-swizzle key (frag rows share l15&7)
    #pragma unroll
    for (int kc = 0; kc < 8; ++kc) {
        // counted wait: kc's 6 loads landed; kc+1's (6 newer) may stay in flight
        if (kc < 7) { asm volatile("s_waitcnt vmcnt(6)" ::: "memory"); }
        else        { asm volatile("s_waitcnt vmcnt(0)" ::: "memory"); }
        __builtin_amdgcn_s_barrier();
        asm volatile("" ::: "memory");   // pin ds_reads below the barrier

        const int base = (kc & 1) * 12288;
        #pragma unroll
        for (int kk2 = 0; kk2 < 2; ++kk2) {
            const int cc = (kk2 * 4 + g) ^ sxor;
            short8_t af[4], bf[2];
            #pragma unroll
            for (int mt = 0; mt < 4; ++mt)
                af[mt] = *(const short8_t*)(smem + base + (16 * mt + l15) * 64 + cc * 8);
            #pragma unroll
            for (int ni = 0; ni < 2; ++ni)
                bf[ni] = *(const short8_t*)(smem + base + 4096
                                            + (32 * w + 16 * ni + l15) * 64 + cc * 8);
            #pragma unroll
            for (int mt = 0; mt < 4; ++mt)
                #pragma unroll
                for (int ni = 0; ni < 2; ++ni)
                    acc1[mt][ni] = __builtin_amdgcn_mfma_f32_16x16x32_bf16(
                        af[mt], bf[ni], acc1[mt][ni], 0, 0, 0);
        }

        asm volatile("" ::: "memory");   // reads consumed (lgkm drained via MFMA deps)
        __builtin_amdgcn_s_barrier();    // all waves done with buf[kc&1]
        if (kc < 6) STAGE1(kc + 2, kc & 1);
    }

    // ---- phase-2 deep prefetch: segs 0,1,2 issued before the h1 barrier ----
    // seg -> rs_local = seg>>2, nt = seg&3; offset = rsl*H2*H1 + nt*16*H1
    const unsigned short* W2base = W2b + (size_t)(c * 12 + w * 3) * (H2_ * H1_)
                                 + (size_t)l15 * H1_ + 8 * g;
    short8_t bfr[4][4];
    #pragma unroll
    for (int ps = 0; ps < 3; ++ps) {
        const unsigned short* nb = W2base + (size_t)(ps >> 2) * (H2_ * H1_)
                                 + (ps & 3) * (16 * H1_);
        #pragma unroll
        for (int kk = 0; kk < 4; ++kk)
            bfr[ps][kk] = *(const short8_t*)(nb + kk * 32);
    }

    // bias + relu -> h1s [64][136] in smem buf0 region (8704 ush <= 12288)
    unsigned short* h1s = smem;
    #pragma unroll
    for (int ni = 0; ni < 2; ++ni) {
        const int i = 32 * w + 16 * ni + l15;
        const float b1v = b1[c * H1_ + i];
        #pragma unroll
        for (int mt = 0; mt < 4; ++mt)
            #pragma unroll
            for (int r = 0; r < 4; ++r) {
                float h = acc1[mt][ni][r] + b1v;
                h = h > 0.f ? h : 0.f;
                h1s[(16 * mt + 4 * g + r) * 136 + i] = f2bf(h);
            }
    }
    __syncthreads();

    // ---------------- Phase 2 ----------------
    short8_t a2[4][4];
    #pragma unroll
    for (int mt = 0; mt < 4; ++mt)
        #pragma unroll
        for (int kk = 0; kk < 4; ++kk)
            a2[mt][kk] = *(const short8_t*)&h1s[(16 * mt + l15) * 136 + 32 * kk + 8 * g];

    float w3v[4], b2v[4];
    #pragma unroll
    for (int nt = 0; nt < 4; ++nt) {
        w3v[nt] = W3[c * H2_ + 16 * nt + l15];
        b2v[nt] = b2[c * H2_ + 16 * nt + l15];
    }
    const float b3v = b3[c];
    const int p = pq >> 2, q = pq & 3;

    float s[4][4];
    #pragma unroll
    for (int mt = 0; mt < 4; ++mt) { s[mt][0] = s[mt][1] = s[mt][2] = s[mt][3] = 0.f; }

    // seg = 0..11 : rs_local = seg>>2, nt = seg&3 ; 3-ahead 4-slot prefetch
    #pragma unroll
    for (int seg = 0; seg < 12; ++seg) {
        if (seg < 9) {
            const int ns = seg + 3;
            const unsigned short* nb = W2base + (size_t)(ns >> 2) * (H2_ * H1_)
                                     + (ns & 3) * (16 * H1_);
            #pragma unroll
            for (int kk = 0; kk < 4; ++kk)
                bfr[ns & 3][kk] = *(const short8_t*)(nb + kk * 32);
        }
        const int nt = seg & 3;
        #pragma unroll
        for (int mt = 0; mt < 4; ++mt) {
            f32x4 acc2 = (f32x4){0.f, 0.f, 0.f, 0.f};
            #pragma unroll
            for (int kk = 0; kk < 4; ++kk)
                acc2 = __builtin_amdgcn_mfma_f32_16x16x32_bf16(
                    a2[mt][kk], bfr[seg & 3][kk], acc2, 0, 0, 0);
            #pragma unroll
            for (int r = 0; r < 4; ++r)
                s[mt][r] += w3v[nt] * fmaxf(acc2[r] + b2v[nt], 0.f);
        }

        if (nt == 3) {
            const int rs = w * 3 + (seg >> 2);
            const int hrow = p * 3 + (rs >> 2), wcol = q * 4 + (rs & 3);
            #pragma unroll
            for (int mt = 0; mt < 4; ++mt)
                #pragma unroll
                for (int r = 0; r < 4; ++r) {
                    float v = s[mt][r];
                    v += __shfl_xor(v, 1); v += __shfl_xor(v, 2);
                    v += __shfl_xor(v, 4); v += __shfl_xor(v, 8);
                    if (l15 == 0) {
                        const int t = 16 * mt + 4 * g + r;
                        if (t < T_)
                            out[(((size_t)b * T_ + t) * 9 + hrow) * 16 + wcol] =
                                1.f / (1.f + __expf(-(v + b3v)));
                    }
                    s[mt][r] = 0.f;
                }
        }
    }
    #undef STAGE1
}

// ---------------------------------------------------------------------------
// fp32 VALU fallback — used only if ws too small
// ---------------------------------------------------------------------------
__global__ __launch_bounds__(256) void fused_decoder_f32(
    const float* __restrict__ x,   const int* __restrict__ cam,
    const float* __restrict__ W1,  const float* __restrict__ b1,
    const float* __restrict__ W2,  const float* __restrict__ b2,
    const float* __restrict__ W3,  const float* __restrict__ b3,
    float* __restrict__ out)
{
    __shared__ float h1s[T_ * H1_];
    __shared__ float stage[8192];

    const int pq  = blockIdx.x;
    const int b   = blockIdx.y;
    const int p   = pq >> 2, q = pq & 3;
    const int tid = threadIdx.x;
    const int c   = cam[b];

    float* xs  = stage;
    float* w1s = stage + 2048;

    const int ig = tid & 31;
    const int tg = tid >> 5;

    float acc[8][4];
    #pragma unroll
    for (int a = 0; a < 8; ++a)
        #pragma unroll
        for (int j = 0; j < 4; ++j) acc[a][j] = 0.f;

    for (int f0 = 0; f0 < F_; f0 += 32) {
        __syncthreads();
        {
            int lane = tid & 63;
            int sub  = tid >> 6;
            if (lane < T_) {
                #pragma unroll
                for (int m = 0; m < 8; ++m) {
                    int kk = sub * 8 + m;
                    xs[kk * 64 + lane] = x[((size_t)b * F_ + f0 + kk) * T_ + lane];
                }
            }
        }
        for (int e = tid; e < 32 * H1_; e += 256) {
            int kk = e >> 7, i = e & 127;
            w1s[e] = W1[(((size_t)c * F_ + f0 + kk) * H1_ + i) * 12 + pq];
        }
        __syncthreads();
        #pragma unroll 8
        for (int kk = 0; kk < 32; ++kk) {
            float4 bv = *(const float4*)&w1s[kk * 128 + ig * 4];
            float4 a0 = *(const float4*)&xs[kk * 64 + tg * 8];
            float4 a1 = *(const float4*)&xs[kk * 64 + tg * 8 + 4];
            float at[8] = {a0.x, a0.y, a0.z, a0.w, a1.x, a1.y, a1.z, a1.w};
            #pragma unroll
            for (int tt = 0; tt < 8; ++tt) {
                acc[tt][0] = fmaf(at[tt], bv.x, acc[tt][0]);
                acc[tt][1] = fmaf(at[tt], bv.y, acc[tt][1]);
                acc[tt][2] = fmaf(at[tt], bv.z, acc[tt][2]);
                acc[tt][3] = fmaf(at[tt], bv.w, acc[tt][3]);
            }
        }
    }
    {
        float4 b1v = *(const float4*)&b1[c * H1_ + ig * 4];
        #pragma unroll
        for (int tt = 0; tt < 8; ++tt) {
            int t = tg * 8 + tt;
            if (t < T_) {
                float4 hv;
                hv.x = fmaxf(acc[tt][0] + b1v.x, 0.f);
                hv.y = fmaxf(acc[tt][1] + b1v.y, 0.f);
                hv.z = fmaxf(acc[tt][2] + b1v.z, 0.f);
                hv.w = fmaxf(acc[tt][3] + b1v.w, 0.f);
                *(float4*)&h1s[t * H1_ + ig * 4] = hv;
            }
        }
    }

    const int lane = tid & 63;
    const int wv   = tid >> 6;
    const float w3v = W3[c * H2_ + lane];
    const float b2v = b2[c * H2_ + lane];
    const float b3v = b3[c];
    float* w2s = stage;

    for (int rs = 0; rs < 12; ++rs) {
        __syncthreads();
        for (int e = tid; e < H1_ * H2_; e += 256) {
            int i = e >> 6, o = e & 63;
            w2s[e] = W2[(((size_t)c * H1_ + i) * H2_ + o) * 12 + rs];
        }
        __syncthreads();

        float acc2[15];
        #pragma unroll
        for (int j = 0; j < 15; ++j) acc2[j] = 0.f;

        for (int i = 0; i < H1_; i += 4) {
            float wa = w2s[(i + 0) * 64 + lane];
            float wb = w2s[(i + 1) * 64 + lane];
            float wc = w2s[(i + 2) * 64 + lane];
            float wd = w2s[(i + 3) * 64 + lane];
            #pragma unroll
            for (int j = 0; j < 15; ++j) {
                float4 h = *(const float4*)&h1s[(wv * 15 + j) * H1_ + i];
                acc2[j] = fmaf(h.x, wa, acc2[j]);
                acc2[j] = fmaf(h.y, wb, acc2[j]);
                acc2[j] = fmaf(h.z, wc, acc2[j]);
                acc2[j] = fmaf(h.w, wd, acc2[j]);
            }
        }

        const int r = rs >> 2, s = rs & 3;
        const int hrow = p * 3 + r, wcol = q * 4 + s;
        #pragma unroll
        for (int j = 0; j < 15; ++j) {
            float y = w3v * fmaxf(acc2[j] + b2v, 0.f);
            #pragma unroll
            for (int m = 32; m > 0; m >>= 1) y += __shfl_xor(y, m, 64);
            if (lane == j) {
                int t = wv * 15 + j;
                float v = y + b3v;
                out[(((size_t)b * T_ + t) * 9 + hrow) * 16 + wcol] = 1.f / (1.f + __expf(-v));
            }
        }
    }
}

// ---------------------------------------------------------------------------
extern "C" void kernel_launch(void* const* d_in, const int* in_sizes, int n_in,
                              void* d_out, int out_size, void* d_ws, size_t ws_size,
                              hipStream_t stream) {
    const float* x   = (const float*)d_in[0];
    const int*   cam = (const int*)  d_in[1];
    const float* W1  = (const float*)d_in[2];
    const float* b1  = (const float*)d_in[3];
    const float* W2  = (const float*)d_in[4];
    const float* b2  = (const float*)d_in[5];
    const float* W3  = (const float*)d_in[6];
    const float* b3  = (const float*)d_in[7];
    float* outp = (float*)d_out;

    const size_t n_xT  = (size_t)B_ * 32768;            //  4,194,304 (swizzled A images)
    const size_t n_w1b = (size_t)C_ * 12 * 65536;       // 11,796,480 (swizzled B images)
    const size_t n_w2b = (size_t)C_ * 12 * H2_ * H1_;   //  1,474,560
    const size_t needed = (n_xT + n_w1b + n_w2b) * sizeof(unsigned short)
                        + B_ * sizeof(int);

    if (d_ws != nullptr && ws_size >= needed) {
        unsigned short* xTs = (unsigned short*)d_ws;
        unsigned short* W1p = xTs + n_xT;
        unsigned short* W2p = W1p + n_w1b;
        int* ord = (int*)(W2p + n_w2b);
        make_order<<<1, 128, 0, stream>>>(cam, ord);
        repack_x <<<dim3(4, B_), 256, 0, stream>>>(x, xTs);
        repack_w1<<<dim3(F_ / 32, H1_ / 32, C_), 256, 0, stream>>>(W1, W1p);
        repack_w2<<<dim3(H1_ / 32, H2_ / 32, C_), 256, 0, stream>>>(W2, W2p);
        fused_mfma<<<dim3(12 * B_), 256, 0, stream>>>(
            xTs, W1p, W2p, cam, ord, b1, b2, W3, b3, outp);
    } else {
        fused_decoder_f32<<<dim3(12, B_), 256, 0, stream>>>(
            x, cam, W1, b1, W2, b2, W3, b3, outp);
    }
}